// Round 3
// baseline (563.427 us; speedup 1.0000x reference)
//
#include <hip/hip_runtime.h>
#include <hip/hip_bf16.h>
#include <math.h>

#define NUM_CLUSTERS 16
#define HIDDEN 1024
#define BOT 128
#define NTOK 65536
#define TM 128

typedef __attribute__((ext_vector_type(8))) short bf16x8;
typedef __attribute__((ext_vector_type(4))) float f32x4;

typedef __attribute__((address_space(3))) unsigned int lds_u32;
typedef const __attribute__((address_space(1))) unsigned int glb_u32;

__device__ __forceinline__ void gload16(const void* g, void* l) {
  __builtin_amdgcn_global_load_lds((glb_u32*)g, (lds_u32*)l, 16, 0, 0);
}

__device__ __forceinline__ unsigned short f2bf(float x) {
  union { float f; unsigned u; } v; v.f = x;
  unsigned r = v.u + 0x7fffu + ((v.u >> 16) & 1u);
  return (unsigned short)(r >> 16);
}

__device__ __forceinline__ bf16x8 pack8(float4 a, float4 b) {
  bf16x8 r;
  r[0] = (short)f2bf(a.x); r[1] = (short)f2bf(a.y);
  r[2] = (short)f2bf(a.z); r[3] = (short)f2bf(a.w);
  r[4] = (short)f2bf(b.x); r[5] = (short)f2bf(b.y);
  r[6] = (short)f2bf(b.z); r[7] = (short)f2bf(b.w);
  return r;
}

// short-index swizzle: XOR byte bits 4..6 with (row&7) => 16B-chunk spread
#define SWZS(row, sidx) ((sidx) ^ (((row) & 7) << 3))

// ---------------- prep kernels ----------------

__global__ void k_zero(int* p) {
  if (threadIdx.x < 64) p[threadIdx.x] = 0;
}

__global__ void k_hist(const int* __restrict__ ids, int* __restrict__ counts) {
  __shared__ int lh[NUM_CLUSTERS];
  if (threadIdx.x < NUM_CLUSTERS) lh[threadIdx.x] = 0;
  __syncthreads();
  int i = blockIdx.x * blockDim.x + threadIdx.x;
  int stride = gridDim.x * blockDim.x;
  for (; i < NTOK; i += stride) atomicAdd(&lh[ids[i]], 1);
  __syncthreads();
  if (threadIdx.x < NUM_CLUSTERS) atomicAdd(&counts[threadIdx.x], lh[threadIdx.x]);
}

__global__ void k_scan(const int* __restrict__ counts, int* __restrict__ offsets,
                       int* __restrict__ cursor) {
  if (threadIdx.x == 0 && blockIdx.x == 0) {
    int s = 0;
    for (int c = 0; c < NUM_CLUSTERS; ++c) {
      offsets[c] = s; cursor[c] = s; s += counts[c];
    }
    offsets[NUM_CLUSTERS] = s;
  }
}

__global__ void k_scatter(const int* __restrict__ ids, int* cursor,
                          int* __restrict__ perm) {
  __shared__ int lh[NUM_CLUSTERS], lbase[NUM_CLUSTERS];
  const int tid = threadIdx.x;
  if (tid < NUM_CLUSTERS) lh[tid] = 0;
  __syncthreads();
  const int i = blockIdx.x * 256 + tid;
  const int cc = ids[i];
  const int r = atomicAdd(&lh[cc], 1);
  __syncthreads();
  if (tid < NUM_CLUSTERS) lbase[tid] = atomicAdd(&cursor[tid], lh[tid]);
  __syncthreads();
  perm[lbase[cc] + r] = i;
}

// Build per-(cluster, k-step) 16KB swizzled LDS images of W1^T:
// image[(n*128 + k'*2) ^ ((n&7)<<4)] = bf16(W1[c][ks*64+k'][n]),  n:0..127, k':0..63
__global__ void k_w1til(const float* __restrict__ W1, unsigned short* __restrict__ outw) {
  const int id = blockIdx.x * 256 + threadIdx.x;   // 262144 total
  const int c  = id >> 14;
  const int ks = (id >> 10) & 15;
  const int q  = id & 1023;
  const int o  = q << 4;                 // stored byte offset in image
  const int row = o >> 7;                // n
  const int lb  = (o & 127) ^ ((row & 7) << 4);
  const int k0  = ks * 64 + (lb >> 1);   // 8 consecutive k
  const float* src = W1 + ((size_t)c * HIDDEN + k0) * BOT + row;
  unsigned short v[8];
  #pragma unroll
  for (int j = 0; j < 8; ++j) v[j] = f2bf(src[(size_t)j * BOT]);
  *(uint4*)((char*)outw + ((size_t)(c * 16 + ks)) * 16384 + o) = *(const uint4*)v;
}

// Build per-(cluster, n-chunk) 32KB swizzled LDS images of W2^T:
// image[(n'*256 + b*2) ^ ((n'&7)<<4)] = bf16(W2[c][b][nc*128+n']),  n':0..127, b:0..127
__global__ void k_w2til(const float* __restrict__ W2, unsigned short* __restrict__ outw) {
  const int id = blockIdx.x * 256 + threadIdx.x;   // 262144 total
  const int c  = id >> 14;
  const int nc = (id >> 11) & 7;
  const int q  = id & 2047;
  const int o  = q << 4;
  const int row = o >> 8;                // n'
  const int lb  = (o & 255) ^ ((row & 7) << 4);
  const int b0  = lb >> 1;               // 8 consecutive b
  const int n   = nc * 128 + row;
  const float* src = W2 + ((size_t)c * BOT + b0) * HIDDEN + n;
  unsigned short v[8];
  #pragma unroll
  for (int j = 0; j < 8; ++j) v[j] = f2bf(src[(size_t)j * HIDDEN]);
  *(uint4*)((char*)outw + ((size_t)(c * 8 + nc)) * 32768 + o) = *(const uint4*)v;
}

// ---------------- fused adapter kernel ----------------
// TM=128 tokens/block, 4 waves in 2x2 (each 64x64 of output tile).
// phase1: mid = gelu(h@W1+b1): 128x128, K=1024, BK=64, gload_lds for W1.
// phase3: out = h + mid@W2 + b2: 8 chunks of 128 cols, K=128, gload_lds for W2.

__global__ __launch_bounds__(256, 2) void k_adapter(
    const float* __restrict__ h, const float* __restrict__ b1g,
    const float* __restrict__ b2g, const unsigned short* __restrict__ W1til,
    const unsigned short* __restrict__ W2til, const int* __restrict__ offsets,
    const int* __restrict__ perm, float* __restrict__ out) {

  // sAB: phase1 = A tile [0,8192) + B1 tile [8192,16384); phase3 = B2 tile (all 32KB)
  __shared__ __align__(16) unsigned short sAB[16384];
  __shared__ __align__(16) unsigned short sMid[16384];
  __shared__ int sTok[TM];

  const int tid = threadIdx.x;
  const int l = tid & 63;
  const int w = tid >> 6;
  const int wr = w >> 1, wc = w & 1;
  const int lr = l & 15, lg = l >> 4;

  // ---- locate (cluster, tile) ----
  int t = blockIdx.x;
  int c;
  bool found = false;
  for (c = 0; c < NUM_CLUSTERS; ++c) {
    int cnt = offsets[c + 1] - offsets[c];
    int nt = (cnt + TM - 1) / TM;
    if (t < nt) { found = true; break; }
    t -= nt;
  }
  if (!found) return;
  const int base = offsets[c] + t * TM;
  const int nvalid = min(TM, offsets[c + 1] - base);

  if (tid < TM) sTok[tid] = perm[base + min(tid, nvalid - 1)];
  __syncthreads();

  const unsigned short* w1base = W1til + (size_t)c * 16 * 8192;   // shorts
  const unsigned short* w2base = W2til + (size_t)c * 8 * 16384;   // shorts

  // A staging roles: thread covers one 32-elem half-row
  const int arow = tid >> 1;      // 0..127
  const int ahalf = tid & 1;      // 0..1
  const long htok = (long)sTok[arow] * HIDDEN;

  f32x4 acc[4][4];
  #pragma unroll
  for (int i = 0; i < 4; ++i)
    #pragma unroll
    for (int j = 0; j < 4; ++j) { f32x4 z = {0.f, 0.f, 0.f, 0.f}; acc[i][j] = z; }

  // ---------------- phase 1: acc = h @ W1 ----------------
  for (int ks = 0; ks < 16; ++ks) {
    __syncthreads();   // prior fragment reads complete
    // issue async B1 staging (16KB image, pre-swizzled)
    const unsigned short* w1s = w1base + ks * 8192;
    #pragma unroll
    for (int j = 0; j < 4; ++j)
      gload16(w1s + j * 2048 + tid * 8, &sAB[8192 + j * 2048 + tid * 8]);
    // reg-stage A: 32 f32 -> 32 bf16, swizzled ds_write
    {
      const float* hp = h + htok + ks * 64 + ahalf * 32;
      float4 v0 = *(const float4*)(hp + 0),  v1 = *(const float4*)(hp + 4);
      float4 v2 = *(const float4*)(hp + 8),  v3 = *(const float4*)(hp + 12);
      float4 v4 = *(const float4*)(hp + 16), v5 = *(const float4*)(hp + 20);
      float4 v6 = *(const float4*)(hp + 24), v7 = *(const float4*)(hp + 28);
      const int sb = arow * 64 + ahalf * 32;
      *(bf16x8*)&sAB[SWZS(arow, sb + 0)]  = pack8(v0, v1);
      *(bf16x8*)&sAB[SWZS(arow, sb + 8)]  = pack8(v2, v3);
      *(bf16x8*)&sAB[SWZS(arow, sb + 16)] = pack8(v4, v5);
      *(bf16x8*)&sAB[SWZS(arow, sb + 24)] = pack8(v6, v7);
    }
    __syncthreads();   // staging + gload drain
    #pragma unroll
    for (int kk = 0; kk < 2; ++kk) {
      bf16x8 af[4], bfr[4];
      #pragma unroll
      for (int mf = 0; mf < 4; ++mf) {
        const int row = wr * 64 + mf * 16 + lr;
        af[mf] = *(const bf16x8*)&sAB[SWZS(row, row * 64 + kk * 32 + lg * 8)];
      }
      #pragma unroll
      for (int nf = 0; nf < 4; ++nf) {
        const int rn = wc * 64 + nf * 16 + lr;
        bfr[nf] = *(const bf16x8*)&sAB[8192 + SWZS(rn, rn * 64 + kk * 32 + lg * 8)];
      }
      #pragma unroll
      for (int mf = 0; mf < 4; ++mf)
        #pragma unroll
        for (int nf = 0; nf < 4; ++nf)
          acc[mf][nf] = __builtin_amdgcn_mfma_f32_16x16x32_bf16(af[mf], bfr[nf], acc[mf][nf], 0, 0, 0);
    }
  }

  // ---------------- phase 2: bias + gelu -> sMid (bf16, swizzled) ----------------
  float b1v[4];
  #pragma unroll
  for (int nf = 0; nf < 4; ++nf) b1v[nf] = b1g[c * BOT + wc * 64 + nf * 16 + lr];
  #pragma unroll
  for (int mf = 0; mf < 4; ++mf) {
    #pragma unroll
    for (int nf = 0; nf < 4; ++nf) {
      #pragma unroll
      for (int r = 0; r < 4; ++r) {
        float x = acc[mf][nf][r] + b1v[nf];
        float g = 0.5f * x * (1.0f + erff(x * 0.70710678118654752f));
        const int m = wr * 64 + mf * 16 + lg * 4 + r;
        const int n = wc * 64 + nf * 16 + lr;
        sMid[SWZS(m, m * 128 + n)] = f2bf(g);
      }
    }
  }

  // ---------------- phase 3: out = h + mid @ W2 + b2 ----------------
  for (int nc = 0; nc < 8; ++nc) {
    __syncthreads();   // prior reads (phase1 tiles / prev B2) complete
    const unsigned short* w2s = w2base + nc * 16384;
    #pragma unroll
    for (int j = 0; j < 8; ++j)
      gload16(w2s + j * 2048 + tid * 8, &sAB[j * 2048 + tid * 8]);
    __syncthreads();   // B2 ready; sMid writes visible

    #pragma unroll
    for (int i = 0; i < 4; ++i)
      #pragma unroll
      for (int j = 0; j < 4; ++j) { f32x4 z = {0.f, 0.f, 0.f, 0.f}; acc[i][j] = z; }

    #pragma unroll
    for (int kk = 0; kk < 4; ++kk) {
      bf16x8 af[4], bfr[4];
      #pragma unroll
      for (int mf = 0; mf < 4; ++mf) {
        const int m = wr * 64 + mf * 16 + lr;
        af[mf] = *(const bf16x8*)&sMid[SWZS(m, m * 128 + kk * 32 + lg * 8)];
      }
      #pragma unroll
      for (int nf = 0; nf < 4; ++nf) {
        const int rn = wc * 64 + nf * 16 + lr;
        bfr[nf] = *(const bf16x8*)&sAB[SWZS(rn, rn * 128 + kk * 32 + lg * 8)];
      }
      #pragma unroll
      for (int mf = 0; mf < 4; ++mf)
        #pragma unroll
        for (int nf = 0; nf < 4; ++nf)
          acc[mf][nf] = __builtin_amdgcn_mfma_f32_16x16x32_bf16(af[mf], bfr[nf], acc[mf][nf], 0, 0, 0);
    }

    // epilogue: residual + b2, predicated scatter-store
    #pragma unroll
    for (int nf = 0; nf < 4; ++nf) {
      const int nn = nc * 128 + wc * 64 + nf * 16 + lr;
      const float b2v = b2g[c * HIDDEN + nn];
      #pragma unroll
      for (int mf = 0; mf < 4; ++mf) {
        #pragma unroll
        for (int r = 0; r < 4; ++r) {
          const int m = wr * 64 + mf * 16 + lg * 4 + r;
          if (m < nvalid) {
            const long tk = (long)sTok[m] * HIDDEN;
            out[tk + nn] = h[tk + nn] + acc[mf][nf][r] + b2v;
          }
        }
      }
    }
  }
}

// ---------------- launcher ----------------
extern "C" void kernel_launch(void* const* d_in, const int* in_sizes, int n_in,
                              void* d_out, int out_size, void* d_ws, size_t ws_size,
                              hipStream_t stream) {
  const float* h   = (const float*)d_in[0];
  const int*   ids = (const int*)d_in[1];
  const float* W1  = (const float*)d_in[2];
  const float* b1  = (const float*)d_in[3];
  const float* W2  = (const float*)d_in[4];
  const float* b2  = (const float*)d_in[5];
  float* out = (float*)d_out;

  char* ws = (char*)d_ws;
  int* counts  = (int*)ws;            // 16 ints
  int* cursor  = (int*)(ws + 64);     // 16 ints
  int* offsets = (int*)(ws + 128);    // 17 ints
  int* perm    = (int*)(ws + 256);    // 65536 ints, ends at 262400
  unsigned short* W1til = (unsigned short*)(ws + 262400);                // 4 MB
  unsigned short* W2til = W1til + (size_t)NUM_CLUSTERS * 16 * 8192;      // 4 MB

  k_zero<<<1, 64, 0, stream>>>(counts);
  k_hist<<<256, 256, 0, stream>>>(ids, counts);
  k_scan<<<1, 64, 0, stream>>>(counts, offsets, cursor);
  k_scatter<<<NTOK / 256, 256, 0, stream>>>(ids, cursor, perm);
  k_w1til<<<1024, 256, 0, stream>>>(W1, W1til);
  k_w2til<<<1024, 256, 0, stream>>>(W2, W2til);

  k_adapter<<<NTOK / TM + NUM_CLUSTERS, 256, 0, stream>>>(
      h, b1, b2, W1til, W2til, offsets, perm, out);
}

// Round 4
// 456.359 us; speedup vs baseline: 1.2346x; 1.2346x over previous
//
#include <hip/hip_runtime.h>
#include <hip/hip_bf16.h>
#include <math.h>

#define NUM_CLUSTERS 16
#define HIDDEN 1024
#define BOT 128
#define NTOK 65536

typedef __attribute__((ext_vector_type(8))) short bf16x8;
typedef __attribute__((ext_vector_type(4))) float f32x4;

typedef __attribute__((address_space(3))) unsigned int lds_u32;
typedef const __attribute__((address_space(1))) unsigned int glb_u32;

__device__ __forceinline__ void gload16(const void* g, void* l) {
  __builtin_amdgcn_global_load_lds((glb_u32*)g, (lds_u32*)l, 16, 0, 0);
}

__device__ __forceinline__ unsigned short f2bf(float x) {
  union { float f; unsigned u; } v; v.f = x;
  unsigned r = v.u + 0x7fffu + ((v.u >> 16) & 1u);
  return (unsigned short)(r >> 16);
}

__device__ __forceinline__ bf16x8 pack8(float4 a, float4 b) {
  bf16x8 r;
  r[0] = (short)f2bf(a.x); r[1] = (short)f2bf(a.y);
  r[2] = (short)f2bf(a.z); r[3] = (short)f2bf(a.w);
  r[4] = (short)f2bf(b.x); r[5] = (short)f2bf(b.y);
  r[6] = (short)f2bf(b.z); r[7] = (short)f2bf(b.w);
  return r;
}

// short-index swizzle: XOR short-idx bits 3..5 with (row&7) -> 16B-chunk spread
#define SWZS(row, sidx) ((sidx) ^ (((row) & 7) << 3))

// bijective XCD-chunk swizzle (m204)
__device__ __forceinline__ int xcd_swz(int bid, int nwg) {
  const int nx = 8;
  int q = nwg / nx, r = nwg % nx;
  int xcd = bid % nx, idx = bid / nx;
  int b = (xcd < r) ? xcd * (q + 1) : r * (q + 1) + (xcd - r) * q;
  return b + idx;
}

// ---------------- prep kernels ----------------

__global__ void k_zero(int* p) {
  if (threadIdx.x < 64) p[threadIdx.x] = 0;
}

__global__ void k_hist(const int* __restrict__ ids, int* __restrict__ counts) {
  __shared__ int lh[NUM_CLUSTERS];
  if (threadIdx.x < NUM_CLUSTERS) lh[threadIdx.x] = 0;
  __syncthreads();
  int i = blockIdx.x * blockDim.x + threadIdx.x;
  int stride = gridDim.x * blockDim.x;
  for (; i < NTOK; i += stride) atomicAdd(&lh[ids[i]], 1);
  __syncthreads();
  if (threadIdx.x < NUM_CLUSTERS) atomicAdd(&counts[threadIdx.x], lh[threadIdx.x]);
}

__global__ void k_scan(const int* __restrict__ counts, int* __restrict__ offsets,
                       int* __restrict__ cursor) {
  if (threadIdx.x == 0 && blockIdx.x == 0) {
    int s = 0;
    for (int c = 0; c < NUM_CLUSTERS; ++c) {
      offsets[c] = s; cursor[c] = s; s += counts[c];
    }
    offsets[NUM_CLUSTERS] = s;
  }
}

__global__ void k_scatter(const int* __restrict__ ids, int* cursor,
                          int* __restrict__ perm) {
  __shared__ int lh[NUM_CLUSTERS], lbase[NUM_CLUSTERS];
  const int tid = threadIdx.x;
  if (tid < NUM_CLUSTERS) lh[tid] = 0;
  __syncthreads();
  const int i = blockIdx.x * 256 + tid;
  const int cc = ids[i];
  const int r = atomicAdd(&lh[cc], 1);
  __syncthreads();
  if (tid < NUM_CLUSTERS) lbase[tid] = atomicAdd(&cursor[tid], lh[tid]);
  __syncthreads();
  perm[lbase[cc] + r] = i;
}

// W1 [16][1024][128] -> per-(c,ks) 16KB swizzled images of W1^T [n=128][k=64]
__global__ void k_w1til(const float* __restrict__ W1, unsigned short* __restrict__ outw) {
  const int id = blockIdx.x * 256 + threadIdx.x;   // 262144 total
  const int c  = id >> 14;
  const int ks = (id >> 10) & 15;
  const int q  = id & 1023;
  const int o  = q << 4;                 // stored byte offset in image
  const int row = o >> 7;                // n
  const int lb  = (o & 127) ^ ((row & 7) << 4);
  const int k0  = ks * 64 + (lb >> 1);   // 8 consecutive k
  const float* src = W1 + ((size_t)c * HIDDEN + k0) * BOT + row;
  unsigned short v[8];
  #pragma unroll
  for (int j = 0; j < 8; ++j) v[j] = f2bf(src[(size_t)j * BOT]);
  *(uint4*)((char*)outw + ((size_t)(c * 16 + ks)) * 16384 + o) = *(const uint4*)v;
}

// W2 [16][128][1024] -> per-(c,nc) 16KB swizzled images of W2^T [n'=64][b=128]
__global__ void k_w2til(const float* __restrict__ W2, unsigned short* __restrict__ outw) {
  const int id = blockIdx.x * 256 + threadIdx.x;   // 262144 total
  const int c  = id >> 14;
  const int nc = (id >> 10) & 15;
  const int q  = id & 1023;
  const int o  = q << 4;
  const int row = o >> 8;                // n' 0..63
  const int lb  = (o & 255) ^ ((row & 7) << 4);
  const int b0  = lb >> 1;               // 8 consecutive b
  const int n   = nc * 64 + row;
  const float* src = W2 + ((size_t)c * BOT + b0) * HIDDEN + n;
  unsigned short v[8];
  #pragma unroll
  for (int j = 0; j < 8; ++j) v[j] = f2bf(src[(size_t)j * HIDDEN]);
  *(uint4*)((char*)outw + ((size_t)(c * 16 + nc)) * 16384 + o) = *(const uint4*)v;
}

// ---- common tile locator: TM tokens per tile ----
__device__ __forceinline__ bool locate(const int* offsets, int bid, int TMv,
                                       int& c, int& base, int& nvalid) {
  int t = bid;
  for (c = 0; c < NUM_CLUSTERS; ++c) {
    int cnt = offsets[c + 1] - offsets[c];
    int nt = (cnt + TMv - 1) / TMv;
    if (t < nt) {
      base = offsets[c] + t * TMv;
      nvalid = min(TMv, offsets[c + 1] - base);
      return true;
    }
    t -= nt;
  }
  return false;
}

// ---------------- pass 1: mid = gelu(h@W1 + b1)  (sorted rows) ----------------
// TM=64 tokens/block; 4 waves 2x2 over 64x128; BK=64, 16 K-steps, dbuf A+B.
#define SA1 72   // A LDS stride (shorts): 64 + 8 pad -> 2-way banks

__global__ __launch_bounds__(256, 3) void k_gemm1(
    const float* __restrict__ h, const float* __restrict__ b1g,
    const unsigned short* __restrict__ W1til, const int* __restrict__ offsets,
    const int* __restrict__ perm, unsigned short* __restrict__ midg) {

  __shared__ __align__(16) unsigned short sA[2][64 * SA1];
  __shared__ __align__(16) unsigned short sB[2][8192];
  __shared__ int sTok[64];

  const int tid = threadIdx.x;
  const int l = tid & 63, w = tid >> 6;
  const int lr = l & 15, lg = l >> 4;
  const int wr = w >> 1, wc = w & 1;

  const int nwg = NTOK / 64 + NUM_CLUSTERS;
  int c, base, nvalid;
  if (!locate(offsets, xcd_swz(blockIdx.x, nwg), 64, c, base, nvalid)) return;

  if (tid < 64) sTok[tid] = perm[base + min(tid, nvalid - 1)];
  __syncthreads();

  const unsigned short* w1base = W1til + (size_t)c * 16 * 8192;
  const int row = tid >> 2, q4 = tid & 3;
  const float* hrow = h + (long)sTok[row] * HIDDEN + q4 * 16;

  // prologue: A(0) regs -> LDS, issue B(0)
  float4 va[4];
  #pragma unroll
  for (int j = 0; j < 4; ++j) va[j] = *(const float4*)(hrow + j * 4);
  #pragma unroll
  for (int j = 0; j < 4; ++j)
    gload16(w1base + j * 2048 + tid * 8, &sB[0][j * 2048 + tid * 8]);
  *(bf16x8*)&sA[0][row * SA1 + q4 * 16]     = pack8(va[0], va[1]);
  *(bf16x8*)&sA[0][row * SA1 + q4 * 16 + 8] = pack8(va[2], va[3]);
  __syncthreads();

  f32x4 acc[2][4];
  #pragma unroll
  for (int i = 0; i < 2; ++i)
    #pragma unroll
    for (int j = 0; j < 4; ++j) { f32x4 z = {0.f, 0.f, 0.f, 0.f}; acc[i][j] = z; }

  for (int t = 0; t < 16; ++t) {
    const int cur = t & 1;
    if (t < 15) {
      // issue A(t+1) FIRST (so its vmcnt wait doesn't drain B(t+1))
      #pragma unroll
      for (int j = 0; j < 4; ++j) va[j] = *(const float4*)(hrow + (t + 1) * 64 + j * 4);
      #pragma unroll
      for (int j = 0; j < 4; ++j)
        gload16(w1base + (t + 1) * 8192 + j * 2048 + tid * 8,
                &sB[cur ^ 1][j * 2048 + tid * 8]);
    }
    #pragma unroll
    for (int kk = 0; kk < 2; ++kk) {
      bf16x8 af[2], bfr[4];
      #pragma unroll
      for (int mf = 0; mf < 2; ++mf) {
        const int m = wr * 32 + mf * 16 + lr;
        af[mf] = *(const bf16x8*)&sA[cur][m * SA1 + kk * 32 + lg * 8];
      }
      #pragma unroll
      for (int nf = 0; nf < 4; ++nf) {
        const int rn = wc * 64 + nf * 16 + lr;
        bfr[nf] = *(const bf16x8*)&sB[cur][SWZS(rn, rn * 64 + kk * 32 + lg * 8)];
      }
      #pragma unroll
      for (int mf = 0; mf < 2; ++mf)
        #pragma unroll
        for (int nf = 0; nf < 4; ++nf)
          acc[mf][nf] = __builtin_amdgcn_mfma_f32_16x16x32_bf16(af[mf], bfr[nf], acc[mf][nf], 0, 0, 0);
    }
    if (t < 15) {
      *(bf16x8*)&sA[cur ^ 1][row * SA1 + q4 * 16]     = pack8(va[0], va[1]);
      *(bf16x8*)&sA[cur ^ 1][row * SA1 + q4 * 16 + 8] = pack8(va[2], va[3]);
    }
    __syncthreads();
  }

  // epilogue: bias + gelu -> midg (bf16, sorted rows)
  float b1v[4];
  #pragma unroll
  for (int nf = 0; nf < 4; ++nf) b1v[nf] = b1g[c * BOT + wc * 64 + nf * 16 + lr];
  #pragma unroll
  for (int mf = 0; mf < 2; ++mf) {
    #pragma unroll
    for (int nf = 0; nf < 4; ++nf) {
      #pragma unroll
      for (int r = 0; r < 4; ++r) {
        float x = acc[mf][nf][r] + b1v[nf];
        float g = 0.5f * x * (1.0f + erff(x * 0.70710678118654752f));
        const int m = wr * 32 + mf * 16 + lg * 4 + r;
        if (m < nvalid) {
          const int n = wc * 64 + nf * 16 + lr;
          midg[(size_t)(base + m) * BOT + n] = f2bf(g);
        }
      }
    }
  }
}

// ---------------- pass 2: out = h + mid@W2 + b2 (scatter) ----------------
// TM=64; 4 waves 2x2 over 64x64 chunks; 16 chunks of 64 cols; dbuf B2.
#define SM2 136  // mid LDS stride (shorts): 128 + 8 pad -> 2-way banks

__global__ __launch_bounds__(256, 3) void k_gemm2(
    const float* __restrict__ h, const float* __restrict__ b2g,
    const unsigned short* __restrict__ W2til, const int* __restrict__ offsets,
    const int* __restrict__ perm, const unsigned short* __restrict__ midg,
    float* __restrict__ out) {

  __shared__ __align__(16) unsigned short sM[64 * SM2];
  __shared__ __align__(16) unsigned short sB[2][8192];
  __shared__ int sTok[64];

  const int tid = threadIdx.x;
  const int l = tid & 63, w = tid >> 6;
  const int lr = l & 15, lg = l >> 4;
  const int wr = w >> 1, wc = w & 1;

  const int nwg = NTOK / 64 + NUM_CLUSTERS;
  int c, base, nvalid;
  if (!locate(offsets, xcd_swz(blockIdx.x, nwg), 64, c, base, nvalid)) return;

  if (tid < 64) sTok[tid] = perm[base + min(tid, nvalid - 1)];

  const unsigned short* w2base = W2til + (size_t)c * 16 * 8192;

  // stage mid tile (64x128 bf16) + issue B2(0)
  {
    const int row = tid >> 2, q = tid & 3;
    const int srow = base + min(row, nvalid - 1);
    const uint4* ms = (const uint4*)(midg + (size_t)srow * BOT + q * 32);
    uint4 m0 = ms[0], m1 = ms[1], m2 = ms[2], m3 = ms[3];
    #pragma unroll
    for (int j = 0; j < 4; ++j)
      gload16(w2base + j * 2048 + tid * 8, &sB[0][j * 2048 + tid * 8]);
    *(uint4*)&sM[row * SM2 + q * 32]      = m0;
    *(uint4*)&sM[row * SM2 + q * 32 + 8]  = m1;
    *(uint4*)&sM[row * SM2 + q * 32 + 16] = m2;
    *(uint4*)&sM[row * SM2 + q * 32 + 24] = m3;
  }
  __syncthreads();

  for (int nc = 0; nc < 16; ++nc) {
    const int cur = nc & 1;
    if (nc < 15) {
      #pragma unroll
      for (int j = 0; j < 4; ++j)
        gload16(w2base + (nc + 1) * 8192 + j * 2048 + tid * 8,
                &sB[cur ^ 1][j * 2048 + tid * 8]);
    }
    f32x4 acc[2][2];
    #pragma unroll
    for (int i = 0; i < 2; ++i)
      #pragma unroll
      for (int j = 0; j < 2; ++j) { f32x4 z = {0.f, 0.f, 0.f, 0.f}; acc[i][j] = z; }

    #pragma unroll
    for (int kk = 0; kk < 4; ++kk) {
      bf16x8 af[2], bfr[2];
      #pragma unroll
      for (int mf = 0; mf < 2; ++mf) {
        const int m = wr * 32 + mf * 16 + lr;
        af[mf] = *(const bf16x8*)&sM[m * SM2 + kk * 32 + lg * 8];
      }
      #pragma unroll
      for (int nf = 0; nf < 2; ++nf) {
        const int rn = wc * 32 + nf * 16 + lr;
        bfr[nf] = *(const bf16x8*)&sB[cur][SWZS(rn, rn * 128 + kk * 32 + lg * 8)];
      }
      #pragma unroll
      for (int mf = 0; mf < 2; ++mf)
        #pragma unroll
        for (int nf = 0; nf < 2; ++nf)
          acc[mf][nf] = __builtin_amdgcn_mfma_f32_16x16x32_bf16(af[mf], bfr[nf], acc[mf][nf], 0, 0, 0);
    }

    // epilogue: residual + b2, scatter RMW
    #pragma unroll
    for (int nf = 0; nf < 2; ++nf) {
      const int nn = nc * 64 + wc * 32 + nf * 16 + lr;
      const float b2v = b2g[c * HIDDEN + nn];
      #pragma unroll
      for (int mf = 0; mf < 2; ++mf) {
        #pragma unroll
        for (int r = 0; r < 4; ++r) {
          const int m = wr * 32 + mf * 16 + lg * 4 + r;
          if (m < nvalid) {
            const long tk = (long)sTok[m] * HIDDEN;
            out[tk + nn] = h[tk + nn] + acc[mf][nf][r] + b2v;
          }
        }
      }
    }
    __syncthreads();
  }
}

// ---------------- fallback fused kernel (ws too small): TM=128 ----------------
#define FSWZ(row, sidx) ((sidx) ^ (((row) & 7) << 3))

__global__ __launch_bounds__(256, 2) void k_fused(
    const float* __restrict__ h, const float* __restrict__ b1g,
    const float* __restrict__ b2g, const unsigned short* __restrict__ W1til,
    const unsigned short* __restrict__ W2til, const int* __restrict__ offsets,
    const int* __restrict__ perm, float* __restrict__ out) {

  __shared__ __align__(16) unsigned short sAB[16384];
  __shared__ __align__(16) unsigned short sMid[16384];
  __shared__ int sTok[128];

  const int tid = threadIdx.x;
  const int l = tid & 63, w = tid >> 6;
  const int wr = w >> 1, wc = w & 1;
  const int lr = l & 15, lg = l >> 4;

  int c, base, nvalid;
  if (!locate(offsets, blockIdx.x, 128, c, base, nvalid)) return;

  if (tid < 128) sTok[tid] = perm[base + min(tid, nvalid - 1)];
  __syncthreads();

  const unsigned short* w1base = W1til + (size_t)c * 16 * 8192;
  const unsigned short* w2base = W2til + (size_t)c * 16 * 8192;

  const int arow = tid >> 1, ahalf = tid & 1;
  const long htok = (long)sTok[arow] * HIDDEN;

  f32x4 acc[4][4];
  #pragma unroll
  for (int i = 0; i < 4; ++i)
    #pragma unroll
    for (int j = 0; j < 4; ++j) { f32x4 z = {0.f, 0.f, 0.f, 0.f}; acc[i][j] = z; }

  for (int ks = 0; ks < 16; ++ks) {
    __syncthreads();
    const unsigned short* w1s = w1base + ks * 8192;
    #pragma unroll
    for (int j = 0; j < 4; ++j)
      gload16(w1s + j * 2048 + tid * 8, &sAB[8192 + j * 2048 + tid * 8]);
    {
      const float* hp = h + htok + ks * 64 + ahalf * 32;
      float4 v0 = *(const float4*)(hp + 0),  v1 = *(const float4*)(hp + 4);
      float4 v2 = *(const float4*)(hp + 8),  v3 = *(const float4*)(hp + 12);
      float4 v4 = *(const float4*)(hp + 16), v5 = *(const float4*)(hp + 20);
      float4 v6 = *(const float4*)(hp + 24), v7 = *(const float4*)(hp + 28);
      const int sb = arow * 64 + ahalf * 32;
      *(bf16x8*)&sAB[FSWZ(arow, sb + 0)]  = pack8(v0, v1);
      *(bf16x8*)&sAB[FSWZ(arow, sb + 8)]  = pack8(v2, v3);
      *(bf16x8*)&sAB[FSWZ(arow, sb + 16)] = pack8(v4, v5);
      *(bf16x8*)&sAB[FSWZ(arow, sb + 24)] = pack8(v6, v7);
    }
    __syncthreads();
    #pragma unroll
    for (int kk = 0; kk < 2; ++kk) {
      bf16x8 af[4], bfr[4];
      #pragma unroll
      for (int mf = 0; mf < 4; ++mf) {
        const int row = wr * 64 + mf * 16 + lr;
        af[mf] = *(const bf16x8*)&sAB[FSWZ(row, row * 64 + kk * 32 + lg * 8)];
      }
      #pragma unroll
      for (int nf = 0; nf < 4; ++nf) {
        const int rn = wc * 64 + nf * 16 + lr;
        bfr[nf] = *(const bf16x8*)&sAB[8192 + FSWZ(rn, rn * 64 + kk * 32 + lg * 8)];
      }
      #pragma unroll
      for (int mf = 0; mf < 4; ++mf)
        #pragma unroll
        for (int nf = 0; nf < 4; ++nf)
          acc[mf][nf] = __builtin_amdgcn_mfma_f32_16x16x32_bf16(af[mf], bfr[nf], acc[mf][nf], 0, 0, 0);
    }
  }

  float b1v[4];
  #pragma unroll
  for (int nf = 0; nf < 4; ++nf) b1v[nf] = b1g[c * BOT + wc * 64 + nf * 16 + lr];
  #pragma unroll
  for (int mf = 0; mf < 4; ++mf)
    #pragma unroll
    for (int nf = 0; nf < 4; ++nf)
      #pragma unroll
      for (int r = 0; r < 4; ++r) {
        float x = acc[mf][nf][r] + b1v[nf];
        float g = 0.5f * x * (1.0f + erff(x * 0.70710678118654752f));
        const int m = wr * 64 + mf * 16 + lg * 4 + r;
        const int n = wc * 64 + nf * 16 + lr;
        sMid[FSWZ(m, m * 128 + n)] = f2bf(g);
      }

  for (int nc = 0; nc < 16; ++nc) {
    __syncthreads();
    #pragma unroll
    for (int j = 0; j < 4; ++j)
      gload16(w2base + nc * 8192 + j * 2048 + tid * 8, &sAB[j * 2048 + tid * 8]);
    __syncthreads();

    f32x4 a2[4][2];
    #pragma unroll
    for (int i = 0; i < 4; ++i)
      #pragma unroll
      for (int j = 0; j < 2; ++j) { f32x4 z = {0.f, 0.f, 0.f, 0.f}; a2[i][j] = z; }

    #pragma unroll
    for (int kk = 0; kk < 4; ++kk) {
      bf16x8 af[4], bfr[2];
      #pragma unroll
      for (int mf = 0; mf < 4; ++mf) {
        const int m = wr * 64 + mf * 16 + lr;
        af[mf] = *(const bf16x8*)&sMid[FSWZ(m, m * 128 + kk * 32 + lg * 8)];
      }
      #pragma unroll
      for (int nf = 0; nf < 2; ++nf) {
        const int rn = wc * 32 + nf * 16 + lr;
        bfr[nf] = *(const bf16x8*)&sAB[FSWZ(rn, rn * 128 + kk * 32 + lg * 8)];
      }
      #pragma unroll
      for (int mf = 0; mf < 4; ++mf)
        #pragma unroll
        for (int nf = 0; nf < 2; ++nf)
          a2[mf][nf] = __builtin_amdgcn_mfma_f32_16x16x32_bf16(af[mf], bfr[nf], a2[mf][nf], 0, 0, 0);
    }

    #pragma unroll
    for (int nf = 0; nf < 2; ++nf) {
      const int nn = nc * 64 + wc * 32 + nf * 16 + lr;
      const float b2v = b2g[c * HIDDEN + nn];
      #pragma unroll
      for (int mf = 0; mf < 4; ++mf)
        #pragma unroll
        for (int r = 0; r < 4; ++r) {
          const int m = wr * 64 + mf * 16 + lg * 4 + r;
          if (m < nvalid) {
            const long tk = (long)sTok[m] * HIDDEN;
            out[tk + nn] = h[tk + nn] + a2[mf][nf][r] + b2v;
          }
        }
    }
  }
}

// ---------------- launcher ----------------
extern "C" void kernel_launch(void* const* d_in, const int* in_sizes, int n_in,
                              void* d_out, int out_size, void* d_ws, size_t ws_size,
                              hipStream_t stream) {
  const float* h   = (const float*)d_in[0];
  const int*   ids = (const int*)d_in[1];
  const float* W1  = (const float*)d_in[2];
  const float* b1  = (const float*)d_in[3];
  const float* W2  = (const float*)d_in[4];
  const float* b2  = (const float*)d_in[5];
  float* out = (float*)d_out;

  char* ws = (char*)d_ws;
  int* counts  = (int*)ws;            // 16 ints
  int* cursor  = (int*)(ws + 64);     // 16 ints
  int* offsets = (int*)(ws + 128);    // 17 ints
  int* perm    = (int*)(ws + 256);    // 65536 ints, ends at 262400
  unsigned short* W1til = (unsigned short*)(ws + 262400);             // 4 MB
  unsigned short* W2til = W1til + (size_t)16 * 16 * 8192;             // 4 MB
  unsigned short* midg  = W2til + (size_t)16 * 16 * 8192;             // 16 MB
  const size_t need = 262400 + 2 * (size_t)16 * 16 * 8192 * 2 +
                      (size_t)NTOK * BOT * 2;

  k_zero<<<1, 64, 0, stream>>>(counts);
  k_hist<<<256, 256, 0, stream>>>(ids, counts);
  k_scan<<<1, 64, 0, stream>>>(counts, offsets, cursor);
  k_scatter<<<NTOK / 256, 256, 0, stream>>>(ids, cursor, perm);
  k_w1til<<<1024, 256, 0, stream>>>(W1, W1til);
  k_w2til<<<1024, 256, 0, stream>>>(W2, W2til);

  if (ws_size >= need) {
    const int nwg = NTOK / 64 + NUM_CLUSTERS;
    k_gemm1<<<nwg, 256, 0, stream>>>(h, b1, W1til, offsets, perm, midg);
    k_gemm2<<<nwg, 256, 0, stream>>>(h, b2, W2til, offsets, perm, midg, out);
  } else {
    k_fused<<<NTOK / 128 + NUM_CLUSTERS, 256, 0, stream>>>(
        h, b1, b2, W1til, W2til, offsets, perm, out);
  }
}

// Round 5
// 290.580 us; speedup vs baseline: 1.9390x; 1.5705x over previous
//
#include <hip/hip_runtime.h>
#include <hip/hip_bf16.h>
#include <math.h>

#define NUM_CLUSTERS 16
#define HIDDEN 1024
#define BOT 128
#define NTOK 65536

typedef __attribute__((ext_vector_type(8))) short bf16x8;
typedef __attribute__((ext_vector_type(4))) float f32x4;

typedef __attribute__((address_space(3))) unsigned int lds_u32;
typedef const __attribute__((address_space(1))) unsigned int glb_u32;

__device__ __forceinline__ void gload16(const void* g, void* l) {
  __builtin_amdgcn_global_load_lds((glb_u32*)g, (lds_u32*)l, 16, 0, 0);
}

__device__ __forceinline__ unsigned short f2bf(float x) {
  union { float f; unsigned u; } v; v.f = x;
  unsigned r = v.u + 0x7fffu + ((v.u >> 16) & 1u);
  return (unsigned short)(r >> 16);
}

__device__ __forceinline__ bf16x8 pack8(float4 a, float4 b) {
  bf16x8 r;
  r[0] = (short)f2bf(a.x); r[1] = (short)f2bf(a.y);
  r[2] = (short)f2bf(a.z); r[3] = (short)f2bf(a.w);
  r[4] = (short)f2bf(b.x); r[5] = (short)f2bf(b.y);
  r[6] = (short)f2bf(b.z); r[7] = (short)f2bf(b.w);
  return r;
}

// short-index swizzle: XOR short-idx bits 3..5 with (row&7) -> 16B-chunk spread
#define SWZS(row, sidx) ((sidx) ^ (((row) & 7) << 3))
// f32-index swizzle (16B granule)
#define SW4(row, fidx) ((fidx) ^ (((row) & 7) << 2))

// bijective XCD-chunk swizzle (m204)
__device__ __forceinline__ int xcd_swz(int bid, int nwg) {
  const int nx = 8;
  int q = nwg / nx, r = nwg % nx;
  int xcd = bid % nx, idx = bid / nx;
  int b = (xcd < r) ? xcd * (q + 1) : r * (q + 1) + (xcd - r) * q;
  return b + idx;
}

// ---------------- prep kernels ----------------

__global__ void k_zero(int* p) {
  if (threadIdx.x < 64) p[threadIdx.x] = 0;
}

__global__ void k_hist(const int* __restrict__ ids, int* __restrict__ counts) {
  __shared__ int lh[NUM_CLUSTERS];
  if (threadIdx.x < NUM_CLUSTERS) lh[threadIdx.x] = 0;
  __syncthreads();
  int i = blockIdx.x * blockDim.x + threadIdx.x;
  int stride = gridDim.x * blockDim.x;
  for (; i < NTOK; i += stride) atomicAdd(&lh[ids[i]], 1);
  __syncthreads();
  if (threadIdx.x < NUM_CLUSTERS) atomicAdd(&counts[threadIdx.x], lh[threadIdx.x]);
}

__global__ void k_scan(const int* __restrict__ counts, int* __restrict__ offsets,
                       int* __restrict__ cursor) {
  if (threadIdx.x == 0 && blockIdx.x == 0) {
    int s = 0;
    for (int c = 0; c < NUM_CLUSTERS; ++c) {
      offsets[c] = s; cursor[c] = s; s += counts[c];
    }
    offsets[NUM_CLUSTERS] = s;
  }
}

__global__ void k_scatter(const int* __restrict__ ids, int* cursor,
                          int* __restrict__ perm) {
  __shared__ int lh[NUM_CLUSTERS], lbase[NUM_CLUSTERS];
  const int tid = threadIdx.x;
  if (tid < NUM_CLUSTERS) lh[tid] = 0;
  __syncthreads();
  const int i = blockIdx.x * 256 + tid;
  const int cc = ids[i];
  const int r = atomicAdd(&lh[cc], 1);
  __syncthreads();
  if (tid < NUM_CLUSTERS) lbase[tid] = atomicAdd(&cursor[tid], lh[tid]);
  __syncthreads();
  perm[lbase[cc] + r] = i;
}

// W1 [16][1024][128] -> per-(c,ks) 16KB swizzled images of W1^T [n=128][k=64]
__global__ void k_w1til(const float* __restrict__ W1, unsigned short* __restrict__ outw) {
  const int id = blockIdx.x * 256 + threadIdx.x;   // 262144 total
  const int c  = id >> 14;
  const int ks = (id >> 10) & 15;
  const int q  = id & 1023;
  const int o  = q << 4;                 // stored byte offset in image
  const int row = o >> 7;                // n
  const int lb  = (o & 127) ^ ((row & 7) << 4);
  const int k0  = ks * 64 + (lb >> 1);   // 8 consecutive k
  const float* src = W1 + ((size_t)c * HIDDEN + k0) * BOT + row;
  unsigned short v[8];
  #pragma unroll
  for (int j = 0; j < 8; ++j) v[j] = f2bf(src[(size_t)j * BOT]);
  *(uint4*)((char*)outw + ((size_t)(c * 16 + ks)) * 16384 + o) = *(const uint4*)v;
}

// W2 [16][128][1024] -> per-(c,nc) 16KB swizzled images of W2^T [n'=64][b=128]
__global__ void k_w2til(const float* __restrict__ W2, unsigned short* __restrict__ outw) {
  const int id = blockIdx.x * 256 + threadIdx.x;   // 262144 total
  const int c  = id >> 14;
  const int nc = (id >> 10) & 15;
  const int q  = id & 1023;
  const int o  = q << 4;
  const int row = o >> 8;                // n' 0..63
  const int lb  = (o & 255) ^ ((row & 7) << 4);
  const int b0  = lb >> 1;               // 8 consecutive b
  const int n   = nc * 64 + row;
  const float* src = W2 + ((size_t)c * BOT + b0) * HIDDEN + n;
  unsigned short v[8];
  #pragma unroll
  for (int j = 0; j < 8; ++j) v[j] = f2bf(src[(size_t)j * HIDDEN]);
  *(uint4*)((char*)outw + ((size_t)(c * 16 + nc)) * 16384 + o) = *(const uint4*)v;
}

// ---- common tile locator: TM tokens per tile ----
__device__ __forceinline__ bool locate(const int* offsets, int bid, int TMv,
                                       int& c, int& base, int& nvalid) {
  int t = bid;
  for (c = 0; c < NUM_CLUSTERS; ++c) {
    int cnt = offsets[c + 1] - offsets[c];
    int nt = (cnt + TMv - 1) / TMv;
    if (t < nt) {
      base = offsets[c] + t * TMv;
      nvalid = min(TMv, offsets[c + 1] - base);
      return true;
    }
    t -= nt;
  }
  return false;
}

// ---------------- pass 1: mid = gelu(h@W1 + b1)  (sorted rows) ----------------
// TM=64 tokens/block; 4 waves 2x2 over 64x128; BK=64, 16 K-steps, dbuf A+B.
#define SA1 72   // A LDS stride (shorts): 64 + 8 pad -> 2-way banks

__global__ __launch_bounds__(256, 3) void k_gemm1(
    const float* __restrict__ h, const float* __restrict__ b1g,
    const unsigned short* __restrict__ W1til, const int* __restrict__ offsets,
    const int* __restrict__ perm, unsigned short* __restrict__ midg) {

  __shared__ __align__(16) unsigned short sA[2][64 * SA1];
  __shared__ __align__(16) unsigned short sB[2][8192];
  __shared__ int sTok[64];

  const int tid = threadIdx.x;
  const int l = tid & 63, w = tid >> 6;
  const int lr = l & 15, lg = l >> 4;
  const int wr = w >> 1, wc = w & 1;

  const int nwg = NTOK / 64 + NUM_CLUSTERS;
  int c, base, nvalid;
  if (!locate(offsets, xcd_swz(blockIdx.x, nwg), 64, c, base, nvalid)) return;

  if (tid < 64) sTok[tid] = perm[base + min(tid, nvalid - 1)];
  __syncthreads();

  const unsigned short* w1base = W1til + (size_t)c * 16 * 8192;
  const int row = tid >> 2, q4 = tid & 3;
  const float* hrow = h + (long)sTok[row] * HIDDEN + q4 * 16;

  // prologue: A(0) regs -> LDS, issue B(0)
  float4 va[4];
  #pragma unroll
  for (int j = 0; j < 4; ++j) va[j] = *(const float4*)(hrow + j * 4);
  #pragma unroll
  for (int j = 0; j < 4; ++j)
    gload16(w1base + j * 2048 + tid * 8, &sB[0][j * 2048 + tid * 8]);
  *(bf16x8*)&sA[0][row * SA1 + q4 * 16]     = pack8(va[0], va[1]);
  *(bf16x8*)&sA[0][row * SA1 + q4 * 16 + 8] = pack8(va[2], va[3]);
  __syncthreads();

  f32x4 acc[2][4];
  #pragma unroll
  for (int i = 0; i < 2; ++i)
    #pragma unroll
    for (int j = 0; j < 4; ++j) { f32x4 z = {0.f, 0.f, 0.f, 0.f}; acc[i][j] = z; }

  for (int t = 0; t < 16; ++t) {
    const int cur = t & 1;
    if (t < 15) {
      #pragma unroll
      for (int j = 0; j < 4; ++j) va[j] = *(const float4*)(hrow + (t + 1) * 64 + j * 4);
      #pragma unroll
      for (int j = 0; j < 4; ++j)
        gload16(w1base + (t + 1) * 8192 + j * 2048 + tid * 8,
                &sB[cur ^ 1][j * 2048 + tid * 8]);
    }
    #pragma unroll
    for (int kk = 0; kk < 2; ++kk) {
      bf16x8 af[2], bfr[4];
      #pragma unroll
      for (int mf = 0; mf < 2; ++mf) {
        const int m = wr * 32 + mf * 16 + lr;
        af[mf] = *(const bf16x8*)&sA[cur][m * SA1 + kk * 32 + lg * 8];
      }
      #pragma unroll
      for (int nf = 0; nf < 4; ++nf) {
        const int rn = wc * 64 + nf * 16 + lr;
        bfr[nf] = *(const bf16x8*)&sB[cur][SWZS(rn, rn * 64 + kk * 32 + lg * 8)];
      }
      #pragma unroll
      for (int mf = 0; mf < 2; ++mf)
        #pragma unroll
        for (int nf = 0; nf < 4; ++nf)
          acc[mf][nf] = __builtin_amdgcn_mfma_f32_16x16x32_bf16(af[mf], bfr[nf], acc[mf][nf], 0, 0, 0);
    }
    if (t < 15) {
      *(bf16x8*)&sA[cur ^ 1][row * SA1 + q4 * 16]     = pack8(va[0], va[1]);
      *(bf16x8*)&sA[cur ^ 1][row * SA1 + q4 * 16 + 8] = pack8(va[2], va[3]);
    }
    __syncthreads();
  }

  // epilogue: bias + gelu -> midg (bf16, sorted rows)
  float b1v[4];
  #pragma unroll
  for (int nf = 0; nf < 4; ++nf) b1v[nf] = b1g[c * BOT + wc * 64 + nf * 16 + lr];
  #pragma unroll
  for (int mf = 0; mf < 2; ++mf) {
    #pragma unroll
    for (int nf = 0; nf < 4; ++nf) {
      #pragma unroll
      for (int r = 0; r < 4; ++r) {
        float x = acc[mf][nf][r] + b1v[nf];
        float g = 0.5f * x * (1.0f + erff(x * 0.70710678118654752f));
        const int m = wr * 32 + mf * 16 + lg * 4 + r;
        if (m < nvalid) {
          const int n = wc * 64 + nf * 16 + lr;
          midg[(size_t)(base + m) * BOT + n] = f2bf(g);
        }
      }
    }
  }
}

// ---------------- pass 2: out = h + mid@W2 + b2 (scatter) ----------------
// 512 threads (8 waves, 2 row-halves x 4 col-quarters); TM=64; 16 chunks x 64 cols.
// Epilogue: acc -> LDS f32 tile (aliased on consumed sB[cur]) -> coalesced float4.

__global__ __launch_bounds__(512, 6) void k_gemm2(
    const float* __restrict__ h, const float* __restrict__ b2g,
    const unsigned short* __restrict__ W2til, const int* __restrict__ offsets,
    const int* __restrict__ perm, const unsigned short* __restrict__ midg,
    float* __restrict__ out) {

  __shared__ __align__(16) unsigned short sM[8192];      // 64x128 bf16, swizzled
  __shared__ __align__(16) unsigned short sB[2][8192];   // 2 x 16KB (chunk images / f32 out tile)
  __shared__ int sTok[64];

  const int tid = threadIdx.x;
  const int l = tid & 63, w = tid >> 6;
  const int lr = l & 15, lg = l >> 4;
  const int wr = w >> 2, wc = w & 3;

  const int nwg = NTOK / 64 + NUM_CLUSTERS;
  int c, base, nvalid;
  if (!locate(offsets, xcd_swz(blockIdx.x, nwg), 64, c, base, nvalid)) return;

  if (tid < 64) sTok[tid] = perm[base + min(tid, nvalid - 1)];

  const unsigned short* w2base = W2til + (size_t)c * 16 * 8192;

  // prologue: issue B(0) gload; stage mid tile (swizzled)
  gload16(w2base + tid * 8, &sB[0][tid * 8]);
  gload16(w2base + 4096 + tid * 8, &sB[0][4096 + tid * 8]);
  {
    const int row = tid >> 3, oct = tid & 7;
    const int srow = base + min(row, nvalid - 1);
    const uint4* ms = (const uint4*)(midg + (size_t)srow * BOT + oct * 16);
    uint4 m0 = ms[0], m1 = ms[1];
    *(uint4*)&sM[SWZS(row, row * 128 + oct * 16)]     = m0;
    *(uint4*)&sM[SWZS(row, row * 128 + oct * 16 + 8)] = m1;
  }
  __syncthreads();

  const int erow = tid >> 3, eo = tid & 7;
  const long etok = (long)sTok[erow] * HIDDEN;
  const float* hrow = h + etok;
  float* orow = out + etok;
  const bool evalid = erow < nvalid;

  for (int nc = 0; nc < 16; ++nc) {
    const int cur = nc & 1;
    if (nc < 15) {
      const unsigned short* w2s = w2base + (nc + 1) * 8192;
      gload16(w2s + tid * 8, &sB[cur ^ 1][tid * 8]);
      gload16(w2s + 4096 + tid * 8, &sB[cur ^ 1][4096 + tid * 8]);
    }
    // T14: prefetch residual h and b2 for this chunk
    float4 hv0 = *(const float4*)(hrow + nc * 64 + eo * 8);
    float4 hv1 = *(const float4*)(hrow + nc * 64 + eo * 8 + 4);
    float4 bv0 = *(const float4*)(b2g + c * HIDDEN + nc * 64 + eo * 8);
    float4 bv1 = *(const float4*)(b2g + c * HIDDEN + nc * 64 + eo * 8 + 4);

    f32x4 acc[2];
    { f32x4 z = {0.f, 0.f, 0.f, 0.f}; acc[0] = z; acc[1] = z; }
    #pragma unroll
    for (int kk = 0; kk < 4; ++kk) {
      bf16x8 af[2], bf1;
      #pragma unroll
      for (int mf = 0; mf < 2; ++mf) {
        const int m = wr * 32 + mf * 16 + lr;
        af[mf] = *(const bf16x8*)&sM[SWZS(m, m * 128 + kk * 32 + lg * 8)];
      }
      const int rn = wc * 16 + lr;
      bf1 = *(const bf16x8*)&sB[cur][SWZS(rn, rn * 128 + kk * 32 + lg * 8)];
      #pragma unroll
      for (int mf = 0; mf < 2; ++mf)
        acc[mf] = __builtin_amdgcn_mfma_f32_16x16x32_bf16(af[mf], bf1, acc[mf], 0, 0, 0);
    }
    __syncthreads();   // all waves done reading sB[cur]

    float* sOutF = (float*)&sB[cur][0];   // 64x64 f32 = 16KB, aliases consumed buffer
    #pragma unroll
    for (int mf = 0; mf < 2; ++mf) {
      #pragma unroll
      for (int r = 0; r < 4; ++r) {
        const int m = wr * 32 + mf * 16 + lg * 4 + r;
        const int n = wc * 16 + lr;
        sOutF[SW4(m, m * 64 + n)] = acc[mf][r];
      }
    }
    __syncthreads();   // f32 tile complete

    if (evalid) {
      const int fb = erow * 64 + eo * 8;
      const float4 y0 = *(const float4*)&sOutF[SW4(erow, fb)];
      const float4 y1 = *(const float4*)&sOutF[SW4(erow, fb + 4)];
      float4 o0, o1;
      o0.x = y0.x + hv0.x + bv0.x; o0.y = y0.y + hv0.y + bv0.y;
      o0.z = y0.z + hv0.z + bv0.z; o0.w = y0.w + hv0.w + bv0.w;
      o1.x = y1.x + hv1.x + bv1.x; o1.y = y1.y + hv1.y + bv1.y;
      o1.z = y1.z + hv1.z + bv1.z; o1.w = y1.w + hv1.w + bv1.w;
      *(float4*)(orow + nc * 64 + eo * 8)     = o0;
      *(float4*)(orow + nc * 64 + eo * 8 + 4) = o1;
    }
    __syncthreads();   // f32-tile reads done before next gload overwrites it
  }
}

// ---------------- fallback fused kernel (ws too small): TM=128 ----------------
#define FSWZ(row, sidx) ((sidx) ^ (((row) & 7) << 3))

__global__ __launch_bounds__(256, 2) void k_fused(
    const float* __restrict__ h, const float* __restrict__ b1g,
    const float* __restrict__ b2g, const unsigned short* __restrict__ W1til,
    const unsigned short* __restrict__ W2til, const int* __restrict__ offsets,
    const int* __restrict__ perm, float* __restrict__ out) {

  __shared__ __align__(16) unsigned short sAB[16384];
  __shared__ __align__(16) unsigned short sMid[16384];
  __shared__ int sTok[128];

  const int tid = threadIdx.x;
  const int l = tid & 63, w = tid >> 6;
  const int wr = w >> 1, wc = w & 1;
  const int lr = l & 15, lg = l >> 4;

  int c, base, nvalid;
  if (!locate(offsets, blockIdx.x, 128, c, base, nvalid)) return;

  if (tid < 128) sTok[tid] = perm[base + min(tid, nvalid - 1)];
  __syncthreads();

  const unsigned short* w1base = W1til + (size_t)c * 16 * 8192;
  const unsigned short* w2base = W2til + (size_t)c * 16 * 8192;

  const int arow = tid >> 1, ahalf = tid & 1;
  const long htok = (long)sTok[arow] * HIDDEN;

  f32x4 acc[4][4];
  #pragma unroll
  for (int i = 0; i < 4; ++i)
    #pragma unroll
    for (int j = 0; j < 4; ++j) { f32x4 z = {0.f, 0.f, 0.f, 0.f}; acc[i][j] = z; }

  for (int ks = 0; ks < 16; ++ks) {
    __syncthreads();
    const unsigned short* w1s = w1base + ks * 8192;
    #pragma unroll
    for (int j = 0; j < 4; ++j)
      gload16(w1s + j * 2048 + tid * 8, &sAB[8192 + j * 2048 + tid * 8]);
    {
      const float* hp = h + htok + ks * 64 + ahalf * 32;
      float4 v0 = *(const float4*)(hp + 0),  v1 = *(const float4*)(hp + 4);
      float4 v2 = *(const float4*)(hp + 8),  v3 = *(const float4*)(hp + 12);
      float4 v4 = *(const float4*)(hp + 16), v5 = *(const float4*)(hp + 20);
      float4 v6 = *(const float4*)(hp + 24), v7 = *(const float4*)(hp + 28);
      const int sb = arow * 64 + ahalf * 32;
      *(bf16x8*)&sAB[FSWZ(arow, sb + 0)]  = pack8(v0, v1);
      *(bf16x8*)&sAB[FSWZ(arow, sb + 8)]  = pack8(v2, v3);
      *(bf16x8*)&sAB[FSWZ(arow, sb + 16)] = pack8(v4, v5);
      *(bf16x8*)&sAB[FSWZ(arow, sb + 24)] = pack8(v6, v7);
    }
    __syncthreads();
    #pragma unroll
    for (int kk = 0; kk < 2; ++kk) {
      bf16x8 af[4], bfr[4];
      #pragma unroll
      for (int mf = 0; mf < 4; ++mf) {
        const int row = wr * 64 + mf * 16 + lr;
        af[mf] = *(const bf16x8*)&sAB[FSWZ(row, row * 64 + kk * 32 + lg * 8)];
      }
      #pragma unroll
      for (int nf = 0; nf < 4; ++nf) {
        const int rn = wc * 64 + nf * 16 + lr;
        bfr[nf] = *(const bf16x8*)&sAB[8192 + FSWZ(rn, rn * 64 + kk * 32 + lg * 8)];
      }
      #pragma unroll
      for (int mf = 0; mf < 4; ++mf)
        #pragma unroll
        for (int nf = 0; nf < 4; ++nf)
          acc[mf][nf] = __builtin_amdgcn_mfma_f32_16x16x32_bf16(af[mf], bfr[nf], acc[mf][nf], 0, 0, 0);
    }
  }

  float b1v[4];
  #pragma unroll
  for (int nf = 0; nf < 4; ++nf) b1v[nf] = b1g[c * BOT + wc * 64 + nf * 16 + lr];
  #pragma unroll
  for (int mf = 0; mf < 4; ++mf)
    #pragma unroll
    for (int nf = 0; nf < 4; ++nf)
      #pragma unroll
      for (int r = 0; r < 4; ++r) {
        float x = acc[mf][nf][r] + b1v[nf];
        float g = 0.5f * x * (1.0f + erff(x * 0.70710678118654752f));
        const int m = wr * 64 + mf * 16 + lg * 4 + r;
        const int n = wc * 64 + nf * 16 + lr;
        sMid[FSWZ(m, m * 128 + n)] = f2bf(g);
      }

  for (int nc = 0; nc < 16; ++nc) {
    __syncthreads();
    #pragma unroll
    for (int j = 0; j < 4; ++j)
      gload16(w2base + nc * 8192 + j * 2048 + tid * 8, &sAB[j * 2048 + tid * 8]);
    __syncthreads();

    f32x4 a2[4][2];
    #pragma unroll
    for (int i = 0; i < 4; ++i)
      #pragma unroll
      for (int j = 0; j < 2; ++j) { f32x4 z = {0.f, 0.f, 0.f, 0.f}; a2[i][j] = z; }

    #pragma unroll
    for (int kk = 0; kk < 4; ++kk) {
      bf16x8 af[4], bfr[2];
      #pragma unroll
      for (int mf = 0; mf < 4; ++mf) {
        const int m = wr * 64 + mf * 16 + lr;
        af[mf] = *(const bf16x8*)&sMid[FSWZ(m, m * 128 + kk * 32 + lg * 8)];
      }
      #pragma unroll
      for (int nf = 0; nf < 2; ++nf) {
        const int rn = wc * 32 + nf * 16 + lr;
        bfr[nf] = *(const bf16x8*)&sAB[FSWZ(rn, rn * 128 + kk * 32 + lg * 8)];
      }
      #pragma unroll
      for (int mf = 0; mf < 4; ++mf)
        #pragma unroll
        for (int nf = 0; nf < 2; ++nf)
          a2[mf][nf] = __builtin_amdgcn_mfma_f32_16x16x32_bf16(af[mf], bfr[nf], a2[mf][nf], 0, 0, 0);
    }

    #pragma unroll
    for (int nf = 0; nf < 2; ++nf) {
      const int nn = nc * 64 + wc * 32 + nf * 16 + lr;
      const float b2v = b2g[c * HIDDEN + nn];
      #pragma unroll
      for (int mf = 0; mf < 4; ++mf)
        #pragma unroll
        for (int r = 0; r < 4; ++r) {
          const int m = wr * 64 + mf * 16 + lg * 4 + r;
          if (m < nvalid) {
            const long tk = (long)sTok[m] * HIDDEN;
            out[tk + nn] = h[tk + nn] + a2[mf][nf][r] + b2v;
          }
        }
    }
  }
}

// ---------------- launcher ----------------
extern "C" void kernel_launch(void* const* d_in, const int* in_sizes, int n_in,
                              void* d_out, int out_size, void* d_ws, size_t ws_size,
                              hipStream_t stream) {
  const float* h   = (const float*)d_in[0];
  const int*   ids = (const int*)d_in[1];
  const float* W1  = (const float*)d_in[2];
  const float* b1  = (const float*)d_in[3];
  const float* W2  = (const float*)d_in[4];
  const float* b2  = (const float*)d_in[5];
  float* out = (float*)d_out;

  char* ws = (char*)d_ws;
  int* counts  = (int*)ws;            // 16 ints
  int* cursor  = (int*)(ws + 64);     // 16 ints
  int* offsets = (int*)(ws + 128);    // 17 ints
  int* perm    = (int*)(ws + 256);    // 65536 ints, ends at 262400
  unsigned short* W1til = (unsigned short*)(ws + 262400);             // 4 MB
  unsigned short* W2til = W1til + (size_t)16 * 16 * 8192;             // 4 MB
  unsigned short* midg  = W2til + (size_t)16 * 16 * 8192;             // 16 MB
  const size_t need = 262400 + 2 * (size_t)16 * 16 * 8192 * 2 +
                      (size_t)NTOK * BOT * 2;

  k_zero<<<1, 64, 0, stream>>>(counts);
  k_hist<<<256, 256, 0, stream>>>(ids, counts);
  k_scan<<<1, 64, 0, stream>>>(counts, offsets, cursor);
  k_scatter<<<NTOK / 256, 256, 0, stream>>>(ids, cursor, perm);
  k_w1til<<<1024, 256, 0, stream>>>(W1, W1til);
  k_w2til<<<1024, 256, 0, stream>>>(W2, W2til);

  if (ws_size >= need) {
    const int nwg = NTOK / 64 + NUM_CLUSTERS;
    k_gemm1<<<nwg, 256, 0, stream>>>(h, b1, W1til, offsets, perm, midg);
    k_gemm2<<<nwg, 512, 0, stream>>>(h, b2, W2til, offsets, perm, midg, out);
  } else {
    k_fused<<<NTOK / 128 + NUM_CLUSTERS, 256, 0, stream>>>(
        h, b1, b2, W1til, W2til, offsets, perm, out);
  }
}

// Round 6
// 278.707 us; speedup vs baseline: 2.0216x; 1.0426x over previous
//
#include <hip/hip_runtime.h>
#include <hip/hip_bf16.h>
#include <math.h>

#define NUM_CLUSTERS 16
#define HIDDEN 1024
#define BOT 128
#define NTOK 65536

typedef __attribute__((ext_vector_type(8))) short bf16x8;
typedef __attribute__((ext_vector_type(4))) float f32x4;

typedef __attribute__((address_space(3))) unsigned int lds_u32;
typedef const __attribute__((address_space(1))) unsigned int glb_u32;

__device__ __forceinline__ void gload16(const void* g, void* l) {
  __builtin_amdgcn_global_load_lds((glb_u32*)g, (lds_u32*)l, 16, 0, 0);
}

__device__ __forceinline__ unsigned short f2bf(float x) {
  union { float f; unsigned u; } v; v.f = x;
  unsigned r = v.u + 0x7fffu + ((v.u >> 16) & 1u);
  return (unsigned short)(r >> 16);
}

__device__ __forceinline__ bf16x8 pack8(float4 a, float4 b) {
  bf16x8 r;
  r[0] = (short)f2bf(a.x); r[1] = (short)f2bf(a.y);
  r[2] = (short)f2bf(a.z); r[3] = (short)f2bf(a.w);
  r[4] = (short)f2bf(b.x); r[5] = (short)f2bf(b.y);
  r[6] = (short)f2bf(b.z); r[7] = (short)f2bf(b.w);
  return r;
}

// short-index swizzle: XOR short-idx bits 3..5 with (row&7) -> 16B-chunk spread
#define SWZS(row, sidx) ((sidx) ^ (((row) & 7) << 3))
// f32-index swizzle (16B granule)
#define SW4(row, fidx) ((fidx) ^ (((row) & 7) << 2))

// bijective XCD-chunk swizzle (m204)
__device__ __forceinline__ int xcd_swz(int bid, int nwg) {
  const int nx = 8;
  int q = nwg / nx, r = nwg % nx;
  int xcd = bid % nx, idx = bid / nx;
  int b = (xcd < r) ? xcd * (q + 1) : r * (q + 1) + (xcd - r) * q;
  return b + idx;
}

// ---------------- prep kernels ----------------

__global__ void k_zero(int* p) {
  if (threadIdx.x < 64) p[threadIdx.x] = 0;
}

__global__ void k_hist(const int* __restrict__ ids, int* __restrict__ counts) {
  __shared__ int lh[NUM_CLUSTERS];
  if (threadIdx.x < NUM_CLUSTERS) lh[threadIdx.x] = 0;
  __syncthreads();
  int i = blockIdx.x * blockDim.x + threadIdx.x;
  int stride = gridDim.x * blockDim.x;
  for (; i < NTOK; i += stride) atomicAdd(&lh[ids[i]], 1);
  __syncthreads();
  if (threadIdx.x < NUM_CLUSTERS) atomicAdd(&counts[threadIdx.x], lh[threadIdx.x]);
}

__global__ void k_scan(const int* __restrict__ counts, int* __restrict__ offsets,
                       int* __restrict__ cursor) {
  if (threadIdx.x == 0 && blockIdx.x == 0) {
    int s = 0;
    for (int c = 0; c < NUM_CLUSTERS; ++c) {
      offsets[c] = s; cursor[c] = s; s += counts[c];
    }
    offsets[NUM_CLUSTERS] = s;
  }
}

__global__ void k_scatter(const int* __restrict__ ids, int* cursor,
                          int* __restrict__ perm) {
  __shared__ int lh[NUM_CLUSTERS], lbase[NUM_CLUSTERS];
  const int tid = threadIdx.x;
  if (tid < NUM_CLUSTERS) lh[tid] = 0;
  __syncthreads();
  const int i = blockIdx.x * 256 + tid;
  const int cc = ids[i];
  const int r = atomicAdd(&lh[cc], 1);
  __syncthreads();
  if (tid < NUM_CLUSTERS) lbase[tid] = atomicAdd(&cursor[tid], lh[tid]);
  __syncthreads();
  perm[lbase[cc] + r] = i;
}

// W1 [16][1024][128] -> per-(c,ks) 16KB swizzled images of W1^T [n=128][k=64]
__global__ void k_w1til(const float* __restrict__ W1, unsigned short* __restrict__ outw) {
  const int id = blockIdx.x * 256 + threadIdx.x;   // 262144 total
  const int c  = id >> 14;
  const int ks = (id >> 10) & 15;
  const int q  = id & 1023;
  const int o  = q << 4;                 // stored byte offset in image
  const int row = o >> 7;                // n
  const int lb  = (o & 127) ^ ((row & 7) << 4);
  const int k0  = ks * 64 + (lb >> 1);   // 8 consecutive k
  const float* src = W1 + ((size_t)c * HIDDEN + k0) * BOT + row;
  unsigned short v[8];
  #pragma unroll
  for (int j = 0; j < 8; ++j) v[j] = f2bf(src[(size_t)j * BOT]);
  *(uint4*)((char*)outw + ((size_t)(c * 16 + ks)) * 16384 + o) = *(const uint4*)v;
}

// W2 [16][128][1024] -> per-(c,nc) 16KB swizzled images of W2^T [n'=64][b=128]
__global__ void k_w2til(const float* __restrict__ W2, unsigned short* __restrict__ outw) {
  const int id = blockIdx.x * 256 + threadIdx.x;   // 262144 total
  const int c  = id >> 14;
  const int nc = (id >> 10) & 15;
  const int q  = id & 1023;
  const int o  = q << 4;
  const int row = o >> 8;                // n' 0..63
  const int lb  = (o & 255) ^ ((row & 7) << 4);
  const int b0  = lb >> 1;               // 8 consecutive b
  const int n   = nc * 64 + row;
  const float* src = W2 + ((size_t)c * BOT + b0) * HIDDEN + n;
  unsigned short v[8];
  #pragma unroll
  for (int j = 0; j < 8; ++j) v[j] = f2bf(src[(size_t)j * HIDDEN]);
  *(uint4*)((char*)outw + ((size_t)(c * 16 + nc)) * 16384 + o) = *(const uint4*)v;
}

// ---- common tile locator: TM tokens per tile ----
__device__ __forceinline__ bool locate(const int* offsets, int bid, int TMv,
                                       int& c, int& base, int& nvalid) {
  int t = bid;
  for (c = 0; c < NUM_CLUSTERS; ++c) {
    int cnt = offsets[c + 1] - offsets[c];
    int nt = (cnt + TMv - 1) / TMv;
    if (t < nt) {
      base = offsets[c] + t * TMv;
      nvalid = min(TMv, offsets[c + 1] - base);
      return true;
    }
    t -= nt;
  }
  return false;
}

// ---------------- pass 1: mid = gelu(h@W1 + b1)  (sorted rows) ----------------
// TM=64; 4 waves 2x2 over 64x128; BK=64, 16 K-steps.
// Counted-vmcnt schedule (T3/T4): raw s_barrier, never drain to 0 mid-loop.
// Issue order per iter t: [B(t+1) gload x4][A(t+2) load x4]; invariant at
// iter top: outstanding = B(t)4, A(t+1)4, B(t+1)4*, A(t+2)4*  (*from this iter).
#define SA1 72   // A LDS stride (shorts): 64 + 8 pad -> 2-way banks

__global__ __launch_bounds__(256, 3) void k_gemm1(
    const float* __restrict__ h, const float* __restrict__ b1g,
    const unsigned short* __restrict__ W1til, const int* __restrict__ offsets,
    const int* __restrict__ perm, unsigned short* __restrict__ midg) {

  __shared__ __align__(16) unsigned short sA[2][64 * SA1];
  __shared__ __align__(16) unsigned short sB[2][8192];
  __shared__ int sTok[64];

  const int tid = threadIdx.x;
  const int l = tid & 63, w = tid >> 6;
  const int lr = l & 15, lg = l >> 4;
  const int wr = w >> 1, wc = w & 1;

  const int nwg = NTOK / 64 + NUM_CLUSTERS;
  int c, base, nvalid;
  if (!locate(offsets, xcd_swz(blockIdx.x, nwg), 64, c, base, nvalid)) return;

  if (tid < 64) sTok[tid] = perm[base + min(tid, nvalid - 1)];
  __syncthreads();

  const unsigned short* w1base = W1til + (size_t)c * 16 * 8192;
  const int row = tid >> 2, q4 = tid & 3;
  const float* hrow = h + (long)sTok[row] * HIDDEN + q4 * 16;

  // prologue: A(0)->vaA, issue B(0), A(1)->vaB, write sA[0]
  float4 vaA[4], vaB[4];
  #pragma unroll
  for (int j = 0; j < 4; ++j) vaA[j] = *(const float4*)(hrow + j * 4);
  #pragma unroll
  for (int j = 0; j < 4; ++j)
    gload16(w1base + j * 2048 + tid * 8, &sB[0][j * 2048 + tid * 8]);
  #pragma unroll
  for (int j = 0; j < 4; ++j) vaB[j] = *(const float4*)(hrow + 64 + j * 4);
  *(bf16x8*)&sA[0][row * SA1 + q4 * 16]     = pack8(vaA[0], vaA[1]);
  *(bf16x8*)&sA[0][row * SA1 + q4 * 16 + 8] = pack8(vaA[2], vaA[3]);
  asm volatile("s_waitcnt lgkmcnt(0)" ::: "memory");
  __builtin_amdgcn_sched_barrier(0);
  __builtin_amdgcn_s_barrier();          // barrier#2(-1): sA[0] visible
  __builtin_amdgcn_sched_barrier(0);

  f32x4 acc[2][4];
  #pragma unroll
  for (int i = 0; i < 2; ++i)
    #pragma unroll
    for (int j = 0; j < 4; ++j) { f32x4 z = {0.f, 0.f, 0.f, 0.f}; acc[i][j] = z; }

  #pragma unroll
  for (int t = 0; t < 16; ++t) {
    const int cur = t & 1;
    // issue B(t+1)
    if (t < 15) {
      const unsigned short* w1s = w1base + (t + 1) * 8192;
      #pragma unroll
      for (int j = 0; j < 4; ++j)
        gload16(w1s + j * 2048 + tid * 8, &sB[cur ^ 1][j * 2048 + tid * 8]);
    }
    // issue A(t+2) into va[t&1] (its previous content consumed at iter t-1)
    if (t < 14) {
      if (t & 1) {
        #pragma unroll
        for (int j = 0; j < 4; ++j) vaB[j] = *(const float4*)(hrow + (t + 2) * 64 + j * 4);
      } else {
        #pragma unroll
        for (int j = 0; j < 4; ++j) vaA[j] = *(const float4*)(hrow + (t + 2) * 64 + j * 4);
      }
    }
    // wait my B(t) done (leave younger prefetches in flight)
    if (t < 14)       asm volatile("s_waitcnt vmcnt(12)" ::: "memory");
    else if (t == 14) asm volatile("s_waitcnt vmcnt(8)" ::: "memory");
    else              asm volatile("s_waitcnt vmcnt(0)" ::: "memory");
    __builtin_amdgcn_sched_barrier(0);
    __builtin_amdgcn_s_barrier();        // barrier#1: B(t) ready everywhere
    __builtin_amdgcn_sched_barrier(0);

    #pragma unroll
    for (int kk = 0; kk < 2; ++kk) {
      bf16x8 af[2], bfr[4];
      #pragma unroll
      for (int mf = 0; mf < 2; ++mf) {
        const int m = wr * 32 + mf * 16 + lr;
        af[mf] = *(const bf16x8*)&sA[cur][m * SA1 + kk * 32 + lg * 8];
      }
      #pragma unroll
      for (int nf = 0; nf < 4; ++nf) {
        const int rn = wc * 64 + nf * 16 + lr;
        bfr[nf] = *(const bf16x8*)&sB[cur][SWZS(rn, rn * 64 + kk * 32 + lg * 8)];
      }
      #pragma unroll
      for (int mf = 0; mf < 2; ++mf)
        #pragma unroll
        for (int nf = 0; nf < 4; ++nf)
          acc[mf][nf] = __builtin_amdgcn_mfma_f32_16x16x32_bf16(af[mf], bfr[nf], acc[mf][nf], 0, 0, 0);
    }

    // stage A(t+1) -> sA[nxt] (compiler auto-waits its vmcnt for va deps)
    if (t < 15) {
      const float4* src = ((t + 1) & 1) ? vaB : vaA;
      *(bf16x8*)&sA[cur ^ 1][row * SA1 + q4 * 16]     = pack8(src[0], src[1]);
      *(bf16x8*)&sA[cur ^ 1][row * SA1 + q4 * 16 + 8] = pack8(src[2], src[3]);
      asm volatile("s_waitcnt lgkmcnt(0)" ::: "memory");
      __builtin_amdgcn_sched_barrier(0);
      __builtin_amdgcn_s_barrier();      // barrier#2: reads done + sA[nxt] ready
      __builtin_amdgcn_sched_barrier(0);
    }
  }

  // epilogue: bias + gelu -> midg (bf16, sorted rows)
  float b1v[4];
  #pragma unroll
  for (int nf = 0; nf < 4; ++nf) b1v[nf] = b1g[c * BOT + wc * 64 + nf * 16 + lr];
  #pragma unroll
  for (int mf = 0; mf < 2; ++mf) {
    #pragma unroll
    for (int nf = 0; nf < 4; ++nf) {
      #pragma unroll
      for (int r = 0; r < 4; ++r) {
        float x = acc[mf][nf][r] + b1v[nf];
        float g = 0.5f * x * (1.0f + erff(x * 0.70710678118654752f));
        const int m = wr * 32 + mf * 16 + lg * 4 + r;
        if (m < nvalid) {
          const int n = wc * 64 + nf * 16 + lr;
          midg[(size_t)(base + m) * BOT + n] = f2bf(g);
        }
      }
    }
  }
}

// ---------------- pass 2: out = h + mid@W2 + b2 (scatter) ----------------
// 512 threads (8 waves, 2 row-halves x 4 col-quarters); TM=64; 16 chunks x 64 cols.
// Epilogue: acc -> LDS f32 tile (aliased on consumed sB[cur]) -> coalesced float4.

__global__ __launch_bounds__(512, 6) void k_gemm2(
    const float* __restrict__ h, const float* __restrict__ b2g,
    const unsigned short* __restrict__ W2til, const int* __restrict__ offsets,
    const int* __restrict__ perm, const unsigned short* __restrict__ midg,
    float* __restrict__ out) {

  __shared__ __align__(16) unsigned short sM[8192];      // 64x128 bf16, swizzled
  __shared__ __align__(16) unsigned short sB[2][8192];   // 2 x 16KB (chunk images / f32 out tile)
  __shared__ int sTok[64];

  const int tid = threadIdx.x;
  const int l = tid & 63, w = tid >> 6;
  const int lr = l & 15, lg = l >> 4;
  const int wr = w >> 2, wc = w & 3;

  const int nwg = NTOK / 64 + NUM_CLUSTERS;
  int c, base, nvalid;
  if (!locate(offsets, xcd_swz(blockIdx.x, nwg), 64, c, base, nvalid)) return;

  if (tid < 64) sTok[tid] = perm[base + min(tid, nvalid - 1)];

  const unsigned short* w2base = W2til + (size_t)c * 16 * 8192;

  // prologue: issue B(0) gload; stage mid tile (swizzled)
  gload16(w2base + tid * 8, &sB[0][tid * 8]);
  gload16(w2base + 4096 + tid * 8, &sB[0][4096 + tid * 8]);
  {
    const int row = tid >> 3, oct = tid & 7;
    const int srow = base + min(row, nvalid - 1);
    const uint4* ms = (const uint4*)(midg + (size_t)srow * BOT + oct * 16);
    uint4 m0 = ms[0], m1 = ms[1];
    *(uint4*)&sM[SWZS(row, row * 128 + oct * 16)]     = m0;
    *(uint4*)&sM[SWZS(row, row * 128 + oct * 16 + 8)] = m1;
  }
  __syncthreads();

  const int erow = tid >> 3, eo = tid & 7;
  const long etok = (long)sTok[erow] * HIDDEN;
  const float* hrow = h + etok;
  float* orow = out + etok;
  const bool evalid = erow < nvalid;

  for (int nc = 0; nc < 16; ++nc) {
    const int cur = nc & 1;
    if (nc < 15) {
      const unsigned short* w2s = w2base + (nc + 1) * 8192;
      gload16(w2s + tid * 8, &sB[cur ^ 1][tid * 8]);
      gload16(w2s + 4096 + tid * 8, &sB[cur ^ 1][4096 + tid * 8]);
    }
    // T14: prefetch residual h and b2 for this chunk
    float4 hv0 = *(const float4*)(hrow + nc * 64 + eo * 8);
    float4 hv1 = *(const float4*)(hrow + nc * 64 + eo * 8 + 4);
    float4 bv0 = *(const float4*)(b2g + c * HIDDEN + nc * 64 + eo * 8);
    float4 bv1 = *(const float4*)(b2g + c * HIDDEN + nc * 64 + eo * 8 + 4);

    f32x4 acc[2];
    { f32x4 z = {0.f, 0.f, 0.f, 0.f}; acc[0] = z; acc[1] = z; }
    #pragma unroll
    for (int kk = 0; kk < 4; ++kk) {
      bf16x8 af[2], bf1;
      #pragma unroll
      for (int mf = 0; mf < 2; ++mf) {
        const int m = wr * 32 + mf * 16 + lr;
        af[mf] = *(const bf16x8*)&sM[SWZS(m, m * 128 + kk * 32 + lg * 8)];
      }
      const int rn = wc * 16 + lr;
      bf1 = *(const bf16x8*)&sB[cur][SWZS(rn, rn * 128 + kk * 32 + lg * 8)];
      #pragma unroll
      for (int mf = 0; mf < 2; ++mf)
        acc[mf] = __builtin_amdgcn_mfma_f32_16x16x32_bf16(af[mf], bf1, acc[mf], 0, 0, 0);
    }
    __syncthreads();   // all waves done reading sB[cur]

    float* sOutF = (float*)&sB[cur][0];   // 64x64 f32 = 16KB, aliases consumed buffer
    #pragma unroll
    for (int mf = 0; mf < 2; ++mf) {
      #pragma unroll
      for (int r = 0; r < 4; ++r) {
        const int m = wr * 32 + mf * 16 + lg * 4 + r;
        const int n = wc * 16 + lr;
        sOutF[SW4(m, m * 64 + n)] = acc[mf][r];
      }
    }
    __syncthreads();   // f32 tile complete

    if (evalid) {
      const int fb = erow * 64 + eo * 8;
      const float4 y0 = *(const float4*)&sOutF[SW4(erow, fb)];
      const float4 y1 = *(const float4*)&sOutF[SW4(erow, fb + 4)];
      float4 o0, o1;
      o0.x = y0.x + hv0.x + bv0.x; o0.y = y0.y + hv0.y + bv0.y;
      o0.z = y0.z + hv0.z + bv0.z; o0.w = y0.w + hv0.w + bv0.w;
      o1.x = y1.x + hv1.x + bv1.x; o1.y = y1.y + hv1.y + bv1.y;
      o1.z = y1.z + hv1.z + bv1.z; o1.w = y1.w + hv1.w + bv1.w;
      *(float4*)(orow + nc * 64 + eo * 8)     = o0;
      *(float4*)(orow + nc * 64 + eo * 8 + 4) = o1;
    }
    __syncthreads();   // f32-tile reads done before next gload overwrites it
  }
}

// ---------------- fallback fused kernel (ws too small): TM=128 ----------------
#define FSWZ(row, sidx) ((sidx) ^ (((row) & 7) << 3))

__global__ __launch_bounds__(256, 2) void k_fused(
    const float* __restrict__ h, const float* __restrict__ b1g,
    const float* __restrict__ b2g, const unsigned short* __restrict__ W1til,
    const unsigned short* __restrict__ W2til, const int* __restrict__ offsets,
    const int* __restrict__ perm, float* __restrict__ out) {

  __shared__ __align__(16) unsigned short sAB[16384];
  __shared__ __align__(16) unsigned short sMid[16384];
  __shared__ int sTok[128];

  const int tid = threadIdx.x;
  const int l = tid & 63, w = tid >> 6;
  const int wr = w >> 1, wc = w & 1;
  const int lr = l & 15, lg = l >> 4;

  int c, base, nvalid;
  if (!locate(offsets, blockIdx.x, 128, c, base, nvalid)) return;

  if (tid < 128) sTok[tid] = perm[base + min(tid, nvalid - 1)];
  __syncthreads();

  const unsigned short* w1base = W1til + (size_t)c * 16 * 8192;
  const unsigned short* w2base = W2til + (size_t)c * 16 * 8192;

  const int arow = tid >> 1, ahalf = tid & 1;
  const long htok = (long)sTok[arow] * HIDDEN;

  f32x4 acc[4][4];
  #pragma unroll
  for (int i = 0; i < 4; ++i)
    #pragma unroll
    for (int j = 0; j < 4; ++j) { f32x4 z = {0.f, 0.f, 0.f, 0.f}; acc[i][j] = z; }

  for (int ks = 0; ks < 16; ++ks) {
    __syncthreads();
    const unsigned short* w1s = w1base + ks * 8192;
    #pragma unroll
    for (int j = 0; j < 4; ++j)
      gload16(w1s + j * 2048 + tid * 8, &sAB[8192 + j * 2048 + tid * 8]);
    {
      const float* hp = h + htok + ks * 64 + ahalf * 32;
      float4 v0 = *(const float4*)(hp + 0),  v1 = *(const float4*)(hp + 4);
      float4 v2 = *(const float4*)(hp + 8),  v3 = *(const float4*)(hp + 12);
      float4 v4 = *(const float4*)(hp + 16), v5 = *(const float4*)(hp + 20);
      float4 v6 = *(const float4*)(hp + 24), v7 = *(const float4*)(hp + 28);
      const int sb = arow * 64 + ahalf * 32;
      *(bf16x8*)&sAB[FSWZ(arow, sb + 0)]  = pack8(v0, v1);
      *(bf16x8*)&sAB[FSWZ(arow, sb + 8)]  = pack8(v2, v3);
      *(bf16x8*)&sAB[FSWZ(arow, sb + 16)] = pack8(v4, v5);
      *(bf16x8*)&sAB[FSWZ(arow, sb + 24)] = pack8(v6, v7);
    }
    __syncthreads();
    #pragma unroll
    for (int kk = 0; kk < 2; ++kk) {
      bf16x8 af[4], bfr[4];
      #pragma unroll
      for (int mf = 0; mf < 4; ++mf) {
        const int row = wr * 64 + mf * 16 + lr;
        af[mf] = *(const bf16x8*)&sAB[FSWZ(row, row * 64 + kk * 32 + lg * 8)];
      }
      #pragma unroll
      for (int nf = 0; nf < 4; ++nf) {
        const int rn = wc * 64 + nf * 16 + lr;
        bfr[nf] = *(const bf16x8*)&sAB[8192 + FSWZ(rn, rn * 64 + kk * 32 + lg * 8)];
      }
      #pragma unroll
      for (int mf = 0; mf < 4; ++mf)
        #pragma unroll
        for (int nf = 0; nf < 4; ++nf)
          acc[mf][nf] = __builtin_amdgcn_mfma_f32_16x16x32_bf16(af[mf], bfr[nf], acc[mf][nf], 0, 0, 0);
    }
  }

  float b1v[4];
  #pragma unroll
  for (int nf = 0; nf < 4; ++nf) b1v[nf] = b1g[c * BOT + wc * 64 + nf * 16 + lr];
  #pragma unroll
  for (int mf = 0; mf < 4; ++mf)
    #pragma unroll
    for (int nf = 0; nf < 4; ++nf)
      #pragma unroll
      for (int r = 0; r < 4; ++r) {
        float x = acc[mf][nf][r] + b1v[nf];
        float g = 0.5f * x * (1.0f + erff(x * 0.70710678118654752f));
        const int m = wr * 64 + mf * 16 + lg * 4 + r;
        const int n = wc * 64 + nf * 16 + lr;
        sMid[FSWZ(m, m * 128 + n)] = f2bf(g);
      }

  for (int nc = 0; nc < 16; ++nc) {
    __syncthreads();
    #pragma unroll
    for (int j = 0; j < 4; ++j)
      gload16(w2base + nc * 8192 + j * 2048 + tid * 8, &sAB[j * 2048 + tid * 8]);
    __syncthreads();

    f32x4 a2[4][2];
    #pragma unroll
    for (int i = 0; i < 4; ++i)
      #pragma unroll
      for (int j = 0; j < 2; ++j) { f32x4 z = {0.f, 0.f, 0.f, 0.f}; a2[i][j] = z; }

    #pragma unroll
    for (int kk = 0; kk < 4; ++kk) {
      bf16x8 af[4], bfr[2];
      #pragma unroll
      for (int mf = 0; mf < 4; ++mf) {
        const int m = wr * 64 + mf * 16 + lr;
        af[mf] = *(const bf16x8*)&sMid[FSWZ(m, m * 128 + kk * 32 + lg * 8)];
      }
      #pragma unroll
      for (int nf = 0; nf < 2; ++nf) {
        const int rn = wc * 32 + nf * 16 + lr;
        bfr[nf] = *(const bf16x8*)&sAB[FSWZ(rn, rn * 128 + kk * 32 + lg * 8)];
      }
      #pragma unroll
      for (int mf = 0; mf < 4; ++mf)
        #pragma unroll
        for (int nf = 0; nf < 2; ++nf)
          a2[mf][nf] = __builtin_amdgcn_mfma_f32_16x16x32_bf16(af[mf], bfr[nf], a2[mf][nf], 0, 0, 0);
    }

    #pragma unroll
    for (int nf = 0; nf < 2; ++nf) {
      const int nn = nc * 64 + wc * 32 + nf * 16 + lr;
      const float b2v = b2g[c * HIDDEN + nn];
      #pragma unroll
      for (int mf = 0; mf < 4; ++mf)
        #pragma unroll
        for (int r = 0; r < 4; ++r) {
          const int m = wr * 64 + mf * 16 + lg * 4 + r;
          if (m < nvalid) {
            const long tk = (long)sTok[m] * HIDDEN;
            out[tk + nn] = h[tk + nn] + a2[mf][nf][r] + b2v;
          }
        }
    }
  }
}

// ---------------- launcher ----------------
extern "C" void kernel_launch(void* const* d_in, const int* in_sizes, int n_in,
                              void* d_out, int out_size, void* d_ws, size_t ws_size,
                              hipStream_t stream) {
  const float* h   = (const float*)d_in[0];
  const int*   ids = (const int*)d_in[1];
  const float* W1  = (const float*)d_in[2];
  const float* b1  = (const float*)d_in[3];
  const float* W2  = (const float*)d_in[4];
  const float* b2  = (const float*)d_in[5];
  float* out = (float*)d_out;

  char* ws = (char*)d_ws;
  int* counts  = (int*)ws;            // 16 ints
  int* cursor  = (int*)(ws + 64);     // 16 ints
  int* offsets = (int*)(ws + 128);    // 17 ints
  int* perm    = (int*)(ws + 256);    // 65536 ints, ends at 262400
  unsigned short* W1til = (unsigned short*)(ws + 262400);             // 4 MB
  unsigned short* W2til = W1til + (size_t)16 * 16 * 8192;             // 4 MB
  unsigned short* midg  = W2til + (size_t)16 * 16 * 8192;             // 16 MB
  const size_t need = 262400 + 2 * (size_t)16 * 16 * 8192 * 2 +
                      (size_t)NTOK * BOT * 2;

  k_zero<<<1, 64, 0, stream>>>(counts);
  k_hist<<<256, 256, 0, stream>>>(ids, counts);
  k_scan<<<1, 64, 0, stream>>>(counts, offsets, cursor);
  k_scatter<<<NTOK / 256, 256, 0, stream>>>(ids, cursor, perm);
  k_w1til<<<1024, 256, 0, stream>>>(W1, W1til);
  k_w2til<<<1024, 256, 0, stream>>>(W2, W2til);

  if (ws_size >= need) {
    const int nwg = NTOK / 64 + NUM_CLUSTERS;
    k_gemm1<<<nwg, 256, 0, stream>>>(h, b1, W1til, offsets, perm, midg);
    k_gemm2<<<nwg, 512, 0, stream>>>(h, b2, W2til, offsets, perm, midg, out);
  } else {
    k_fused<<<NTOK / 128 + NUM_CLUSTERS, 256, 0, stream>>>(
        h, b1, b2, W1til, W2til, offsets, perm, out);
  }
}

// Round 7
// 269.938 us; speedup vs baseline: 2.0872x; 1.0325x over previous
//
#include <hip/hip_runtime.h>
#include <hip/hip_bf16.h>
#include <math.h>

#define NUM_CLUSTERS 16
#define HIDDEN 1024
#define BOT 128
#define NTOK 65536

typedef __attribute__((ext_vector_type(8))) short bf16x8;
typedef __attribute__((ext_vector_type(4))) float f32x4;

typedef __attribute__((address_space(3))) unsigned int lds_u32;
typedef const __attribute__((address_space(1))) unsigned int glb_u32;

__device__ __forceinline__ void gload16(const void* g, void* l) {
  __builtin_amdgcn_global_load_lds((glb_u32*)g, (lds_u32*)l, 16, 0, 0);
}

__device__ __forceinline__ unsigned short f2bf(float x) {
  union { float f; unsigned u; } v; v.f = x;
  unsigned r = v.u + 0x7fffu + ((v.u >> 16) & 1u);
  return (unsigned short)(r >> 16);
}

__device__ __forceinline__ bf16x8 pack8(float4 a, float4 b) {
  bf16x8 r;
  r[0] = (short)f2bf(a.x); r[1] = (short)f2bf(a.y);
  r[2] = (short)f2bf(a.z); r[3] = (short)f2bf(a.w);
  r[4] = (short)f2bf(b.x); r[5] = (short)f2bf(b.y);
  r[6] = (short)f2bf(b.z); r[7] = (short)f2bf(b.w);
  return r;
}

// short-index swizzle: XOR short-idx bits 3..5 with (row&7) -> 16B-chunk spread
#define SWZS(row, sidx) ((sidx) ^ (((row) & 7) << 3))
// f32-index swizzle (16B granule)
#define SW4(row, fidx) ((fidx) ^ (((row) & 7) << 2))

#define VMW(n) asm volatile("s_waitcnt vmcnt(" #n ")" ::: "memory")
#define SBAR()                                  \
  do {                                          \
    __builtin_amdgcn_sched_barrier(0);          \
    __builtin_amdgcn_s_barrier();               \
    __builtin_amdgcn_sched_barrier(0);          \
  } while (0)
#define LGKM0() asm volatile("s_waitcnt lgkmcnt(0)" ::: "memory")

// bijective XCD-chunk swizzle (m204)
__device__ __forceinline__ int xcd_swz(int bid, int nwg) {
  const int nx = 8;
  int q = nwg / nx, r = nwg % nx;
  int xcd = bid % nx, idx = bid / nx;
  int b = (xcd < r) ? xcd * (q + 1) : r * (q + 1) + (xcd - r) * q;
  return b + idx;
}

// ---------------- prep kernels ----------------

__global__ void k_zero(int* p) {
  if (threadIdx.x < 64) p[threadIdx.x] = 0;
}

__global__ void k_hist(const int* __restrict__ ids, int* __restrict__ counts) {
  __shared__ int lh[NUM_CLUSTERS];
  if (threadIdx.x < NUM_CLUSTERS) lh[threadIdx.x] = 0;
  __syncthreads();
  int i = blockIdx.x * blockDim.x + threadIdx.x;
  int stride = gridDim.x * blockDim.x;
  for (; i < NTOK; i += stride) atomicAdd(&lh[ids[i]], 1);
  __syncthreads();
  if (threadIdx.x < NUM_CLUSTERS) atomicAdd(&counts[threadIdx.x], lh[threadIdx.x]);
}

__global__ void k_scan(const int* __restrict__ counts, int* __restrict__ offsets,
                       int* __restrict__ cursor) {
  if (threadIdx.x == 0 && blockIdx.x == 0) {
    int s = 0;
    for (int c = 0; c < NUM_CLUSTERS; ++c) {
      offsets[c] = s; cursor[c] = s; s += counts[c];
    }
    offsets[NUM_CLUSTERS] = s;
  }
}

__global__ void k_scatter(const int* __restrict__ ids, int* cursor,
                          int* __restrict__ perm) {
  __shared__ int lh[NUM_CLUSTERS], lbase[NUM_CLUSTERS];
  const int tid = threadIdx.x;
  if (tid < NUM_CLUSTERS) lh[tid] = 0;
  __syncthreads();
  const int i = blockIdx.x * 256 + tid;
  const int cc = ids[i];
  const int r = atomicAdd(&lh[cc], 1);
  __syncthreads();
  if (tid < NUM_CLUSTERS) lbase[tid] = atomicAdd(&cursor[tid], lh[tid]);
  __syncthreads();
  perm[lbase[cc] + r] = i;
}

// W1 [16][1024][128] -> per-(c,ks) 16KB swizzled images of W1^T [n=128][k=64]
__global__ void k_w1til(const float* __restrict__ W1, unsigned short* __restrict__ outw) {
  const int id = blockIdx.x * 256 + threadIdx.x;   // 262144 total
  const int c  = id >> 14;
  const int ks = (id >> 10) & 15;
  const int q  = id & 1023;
  const int o  = q << 4;                 // stored byte offset in image
  const int row = o >> 7;                // n
  const int lb  = (o & 127) ^ ((row & 7) << 4);
  const int k0  = ks * 64 + (lb >> 1);   // 8 consecutive k
  const float* src = W1 + ((size_t)c * HIDDEN + k0) * BOT + row;
  unsigned short v[8];
  #pragma unroll
  for (int j = 0; j < 8; ++j) v[j] = f2bf(src[(size_t)j * BOT]);
  *(uint4*)((char*)outw + ((size_t)(c * 16 + ks)) * 16384 + o) = *(const uint4*)v;
}

// W2 [16][128][1024] -> per-(c,nc) 16KB swizzled images of W2^T [n'=64][b=128]
__global__ void k_w2til(const float* __restrict__ W2, unsigned short* __restrict__ outw) {
  const int id = blockIdx.x * 256 + threadIdx.x;   // 262144 total
  const int c  = id >> 14;
  const int nc = (id >> 10) & 15;
  const int q  = id & 1023;
  const int o  = q << 4;
  const int row = o >> 8;                // n' 0..63
  const int lb  = (o & 255) ^ ((row & 7) << 4);
  const int b0  = lb >> 1;               // 8 consecutive b
  const int n   = nc * 64 + row;
  const float* src = W2 + ((size_t)c * BOT + b0) * HIDDEN + n;
  unsigned short v[8];
  #pragma unroll
  for (int j = 0; j < 8; ++j) v[j] = f2bf(src[(size_t)j * HIDDEN]);
  *(uint4*)((char*)outw + ((size_t)(c * 16 + nc)) * 16384 + o) = *(const uint4*)v;
}

// ---- common tile locator: TM tokens per tile ----
__device__ __forceinline__ bool locate(const int* offsets, int bid, int TMv,
                                       int& c, int& base, int& nvalid) {
  int t = bid;
  for (c = 0; c < NUM_CLUSTERS; ++c) {
    int cnt = offsets[c + 1] - offsets[c];
    int nt = (cnt + TMv - 1) / TMv;
    if (t < nt) {
      base = offsets[c] + t * TMv;
      nvalid = min(TMv, offsets[c + 1] - base);
      return true;
    }
    t -= nt;
  }
  return false;
}

// ---------------- pass 1: mid = gelu(h@W1 + b1)  (sorted rows) ----------------
// 512 threads (8 waves, 2 row-halves x 4 col-quarters); TM=64; BK=64, 16 K-steps.
// LDS 48KB -> 3 blocks/CU (24 waves). Counted-vmcnt: per thread 2 B-gloads +
// 2 A-float4 per iter; steady outstanding at wait = B(t)2,A(t+1)2,B(t+1)2,A(t+2)2
// -> wait B(t) = vmcnt(6); t=14 -> vmcnt(4); t=15 -> vmcnt(0).

__global__ __launch_bounds__(512, 6) void k_gemm1(
    const float* __restrict__ h, const float* __restrict__ b1g,
    const unsigned short* __restrict__ W1til, const int* __restrict__ offsets,
    const int* __restrict__ perm, unsigned short* __restrict__ midg) {

  __shared__ __align__(16) unsigned short sA[2][4096];   // 64x64 bf16 swizzled
  __shared__ __align__(16) unsigned short sB[2][8192];   // 128n x 64k bf16 swizzled
  __shared__ int sTok[64];

  const int tid = threadIdx.x;
  const int l = tid & 63, w = tid >> 6;
  const int lr = l & 15, lg = l >> 4;
  const int wr = w >> 2, wc = w & 3;      // wave -> (32-row half, 32-col quarter)

  const int nwg = NTOK / 64 + NUM_CLUSTERS;
  int c, base, nvalid;
  if (!locate(offsets, xcd_swz(blockIdx.x, nwg), 64, c, base, nvalid)) return;

  if (tid < 64) sTok[tid] = perm[base + min(tid, nvalid - 1)];
  __syncthreads();

  const unsigned short* w1base = W1til + (size_t)c * 16 * 8192;
  const int row = tid >> 3, o8 = tid & 7;     // A staging: 8 floats/thread
  const float* hrow = h + (long)sTok[row] * HIDDEN + o8 * 8;

  // prologue (issue order matters: A first so pack-wait never drains B)
  float4 vaA[2], vaB[2];
  vaA[0] = *(const float4*)(hrow);       vaA[1] = *(const float4*)(hrow + 4);
  gload16(w1base + tid * 8, &sB[0][tid * 8]);
  gload16(w1base + 4096 + tid * 8, &sB[0][4096 + tid * 8]);
  vaB[0] = *(const float4*)(hrow + 64);  vaB[1] = *(const float4*)(hrow + 68);
  *(bf16x8*)&sA[0][SWZS(row, row * 64 + o8 * 8)] = pack8(vaA[0], vaA[1]);
  LGKM0();
  SBAR();

  f32x4 acc[2][2];
  #pragma unroll
  for (int i = 0; i < 2; ++i)
    #pragma unroll
    for (int j = 0; j < 2; ++j) { f32x4 z = {0.f, 0.f, 0.f, 0.f}; acc[i][j] = z; }

#define G1_MFMA(CUR)                                                          \
  do {                                                                        \
    _Pragma("unroll")                                                         \
    for (int kk = 0; kk < 2; ++kk) {                                          \
      bf16x8 af[2], bfr[2];                                                   \
      _Pragma("unroll")                                                       \
      for (int mf = 0; mf < 2; ++mf) {                                        \
        const int m = wr * 32 + mf * 16 + lr;                                 \
        af[mf] = *(const bf16x8*)&sA[CUR][SWZS(m, m * 64 + kk * 32 + lg * 8)];\
      }                                                                       \
      _Pragma("unroll")                                                       \
      for (int nf = 0; nf < 2; ++nf) {                                        \
        const int rn = wc * 32 + nf * 16 + lr;                                \
        bfr[nf] = *(const bf16x8*)&sB[CUR][SWZS(rn, rn * 64 + kk * 32 + lg * 8)]; \
      }                                                                       \
      _Pragma("unroll")                                                       \
      for (int mf = 0; mf < 2; ++mf)                                          \
        _Pragma("unroll")                                                     \
        for (int nf = 0; nf < 2; ++nf)                                        \
          acc[mf][nf] = __builtin_amdgcn_mfma_f32_16x16x32_bf16(              \
              af[mf], bfr[nf], acc[mf][nf], 0, 0, 0);                         \
    }                                                                         \
  } while (0)

#define G1_ISSUE_B(T, NXT)                                                    \
  do {                                                                        \
    const unsigned short* w1s = w1base + (T + 1) * 8192;                      \
    gload16(w1s + tid * 8, &sB[NXT][tid * 8]);                                \
    gload16(w1s + 4096 + tid * 8, &sB[NXT][4096 + tid * 8]);                  \
  } while (0)

#define G1_STAGE(SRC, NXT)                                                    \
  do {                                                                        \
    *(bf16x8*)&sA[NXT][SWZS(row, row * 64 + o8 * 8)] = pack8(SRC[0], SRC[1]); \
    LGKM0();                                                                  \
    SBAR();                                                                   \
  } while (0)

  for (int tp = 0; tp < 14; tp += 2) {
    // ---- step t=tp (even): cur=0, load A(t+2)->vaA, stage A(t+1) from vaB
    G1_ISSUE_B(tp, 1);
    vaA[0] = *(const float4*)(hrow + (tp + 2) * 64);
    vaA[1] = *(const float4*)(hrow + (tp + 2) * 64 + 4);
    VMW(6);
    SBAR();
    G1_MFMA(0);
    G1_STAGE(vaB, 1);
    // ---- step t=tp+1 (odd): cur=1, load A(t+2)->vaB, stage A(t+1) from vaA
    G1_ISSUE_B(tp + 1, 0);
    vaB[0] = *(const float4*)(hrow + (tp + 3) * 64);
    vaB[1] = *(const float4*)(hrow + (tp + 3) * 64 + 4);
    VMW(6);
    SBAR();
    G1_MFMA(1);
    G1_STAGE(vaA, 0);
  }
  // ---- t=14 (cur=0): issue B(15), no A load; stage A(15) from vaB
  G1_ISSUE_B(14, 1);
  VMW(4);
  SBAR();
  G1_MFMA(0);
  G1_STAGE(vaB, 1);
  // ---- t=15 (cur=1)
  VMW(0);
  SBAR();
  G1_MFMA(1);

  // epilogue: bias + gelu -> midg (bf16, sorted rows)
  float b1v[2];
  #pragma unroll
  for (int nf = 0; nf < 2; ++nf) b1v[nf] = b1g[c * BOT + wc * 32 + nf * 16 + lr];
  #pragma unroll
  for (int mf = 0; mf < 2; ++mf) {
    #pragma unroll
    for (int nf = 0; nf < 2; ++nf) {
      #pragma unroll
      for (int r = 0; r < 4; ++r) {
        float x = acc[mf][nf][r] + b1v[nf];
        float g = 0.5f * x * (1.0f + erff(x * 0.70710678118654752f));
        const int m = wr * 32 + mf * 16 + lg * 4 + r;
        if (m < nvalid) {
          const int n = wc * 32 + nf * 16 + lr;
          midg[(size_t)(base + m) * BOT + n] = f2bf(g);
        }
      }
    }
  }
}

// ---------------- pass 2: out = h + mid@W2 + b2 (scatter) ----------------
// 512 threads; TM=64; 16 chunks x 64 cols. Counted-vmcnt version: hv/bv issued
// BEFORE B(nc+1) gloads; steady wait vmcnt(8) (= st2+hv4+B2 younger than B(nc)),
// nc==0/15 -> vmcnt(6). Raw barriers, no vmcnt(0) in loop.

__global__ __launch_bounds__(512, 6) void k_gemm2(
    const float* __restrict__ h, const float* __restrict__ b2g,
    const unsigned short* __restrict__ W2til, const int* __restrict__ offsets,
    const int* __restrict__ perm, const unsigned short* __restrict__ midg,
    float* __restrict__ out) {

  __shared__ __align__(16) unsigned short sM[8192];      // 64x128 bf16, swizzled
  __shared__ __align__(16) unsigned short sB[2][8192];   // chunk images / f32 out tile
  __shared__ int sTok[64];

  const int tid = threadIdx.x;
  const int l = tid & 63, w = tid >> 6;
  const int lr = l & 15, lg = l >> 4;
  const int wr = w >> 2, wc = w & 3;

  const int nwg = NTOK / 64 + NUM_CLUSTERS;
  int c, base, nvalid;
  if (!locate(offsets, xcd_swz(blockIdx.x, nwg), 64, c, base, nvalid)) return;

  if (tid < 64) sTok[tid] = perm[base + min(tid, nvalid - 1)];

  const unsigned short* w2base = W2til + (size_t)c * 16 * 8192;

  // prologue: mid loads FIRST, then B(0) gloads (so pack-wait leaves B flying)
  {
    const int row = tid >> 3, oct = tid & 7;
    const int srow = base + min(row, nvalid - 1);
    const uint4* ms = (const uint4*)(midg + (size_t)srow * BOT + oct * 16);
    uint4 m0 = ms[0], m1 = ms[1];
    gload16(w2base + tid * 8, &sB[0][tid * 8]);
    gload16(w2base + 4096 + tid * 8, &sB[0][4096 + tid * 8]);
    *(uint4*)&sM[SWZS(row, row * 128 + oct * 16)]     = m0;
    *(uint4*)&sM[SWZS(row, row * 128 + oct * 16 + 8)] = m1;
  }
  LGKM0();
  SBAR();

  const int erow = tid >> 3, eo = tid & 7;
  const long etok = (long)sTok[erow] * HIDDEN;
  const float* hrow = h + etok;
  float* orow = out + etok;
  const bool evalid = erow < nvalid;

  for (int nc = 0; nc < 16; ++nc) {
    const int cur = nc & 1;
    // prefetch residual h and b2 for THIS chunk (issued first!)
    float4 hv0 = *(const float4*)(hrow + nc * 64 + eo * 8);
    float4 hv1 = *(const float4*)(hrow + nc * 64 + eo * 8 + 4);
    float4 bv0 = *(const float4*)(b2g + c * HIDDEN + nc * 64 + eo * 8);
    float4 bv1 = *(const float4*)(b2g + c * HIDDEN + nc * 64 + eo * 8 + 4);
    // issue next chunk's image
    if (nc < 15) {
      const unsigned short* w2s = w2base + (nc + 1) * 8192;
      gload16(w2s + tid * 8, &sB[cur ^ 1][tid * 8]);
      gload16(w2s + 4096 + tid * 8, &sB[cur ^ 1][4096 + tid * 8]);
    }
    // wait B(nc) only (leave younger ops in flight)
    if (nc == 0 || nc == 15) { VMW(6); } else { VMW(8); }
    SBAR();                         // sB[cur] valid across all waves

    f32x4 acc[2];
    { f32x4 z = {0.f, 0.f, 0.f, 0.f}; acc[0] = z; acc[1] = z; }
    #pragma unroll
    for (int kk = 0; kk < 4; ++kk) {
      bf16x8 af[2], bf1;
      #pragma unroll
      for (int mf = 0; mf < 2; ++mf) {
        const int m = wr * 32 + mf * 16 + lr;
        af[mf] = *(const bf16x8*)&sM[SWZS(m, m * 128 + kk * 32 + lg * 8)];
      }
      const int rn = wc * 16 + lr;
      bf1 = *(const bf16x8*)&sB[cur][SWZS(rn, rn * 128 + kk * 32 + lg * 8)];
      #pragma unroll
      for (int mf = 0; mf < 2; ++mf)
        acc[mf] = __builtin_amdgcn_mfma_f32_16x16x32_bf16(af[mf], bf1, acc[mf], 0, 0, 0);
    }
    SBAR();                         // all waves done reading sB[cur]

    float* sOutF = (float*)&sB[cur][0];   // 64x64 f32, aliases consumed buffer
    #pragma unroll
    for (int mf = 0; mf < 2; ++mf) {
      #pragma unroll
      for (int r = 0; r < 4; ++r) {
        const int m = wr * 32 + mf * 16 + lg * 4 + r;
        const int n = wc * 16 + lr;
        sOutF[SW4(m, m * 64 + n)] = acc[mf][r];
      }
    }
    LGKM0();
    SBAR();                         // f32 tile complete

    if (evalid) {
      const int fb = erow * 64 + eo * 8;
      const float4 y0 = *(const float4*)&sOutF[SW4(erow, fb)];
      const float4 y1 = *(const float4*)&sOutF[SW4(erow, fb + 4)];
      float4 o0, o1;
      o0.x = y0.x + hv0.x + bv0.x; o0.y = y0.y + hv0.y + bv0.y;
      o0.z = y0.z + hv0.z + bv0.z; o0.w = y0.w + hv0.w + bv0.w;
      o1.x = y1.x + hv1.x + bv1.x; o1.y = y1.y + hv1.y + bv1.y;
      o1.z = y1.z + hv1.z + bv1.z; o1.w = y1.w + hv1.w + bv1.w;
      *(float4*)(orow + nc * 64 + eo * 8)     = o0;
      *(float4*)(orow + nc * 64 + eo * 8 + 4) = o1;
    }
    SBAR();                         // sOutF reads done before next iter's gload
  }
}

// ---------------- fallback fused kernel (ws too small): TM=128 ----------------
#define FSWZ(row, sidx) ((sidx) ^ (((row) & 7) << 3))

__global__ __launch_bounds__(256, 2) void k_fused(
    const float* __restrict__ h, const float* __restrict__ b1g,
    const float* __restrict__ b2g, const unsigned short* __restrict__ W1til,
    const unsigned short* __restrict__ W2til, const int* __restrict__ offsets,
    const int* __restrict__ perm, float* __restrict__ out) {

  __shared__ __align__(16) unsigned short sAB[16384];
  __shared__ __align__(16) unsigned short sMid[16384];
  __shared__ int sTok[128];

  const int tid = threadIdx.x;
  const int l = tid & 63, w = tid >> 6;
  const int wr = w >> 1, wc = w & 1;
  const int lr = l & 15, lg = l >> 4;

  int c, base, nvalid;
  if (!locate(offsets, blockIdx.x, 128, c, base, nvalid)) return;

  if (tid < 128) sTok[tid] = perm[base + min(tid, nvalid - 1)];
  __syncthreads();

  const unsigned short* w1base = W1til + (size_t)c * 16 * 8192;
  const unsigned short* w2base = W2til + (size_t)c * 16 * 8192;

  const int arow = tid >> 1, ahalf = tid & 1;
  const long htok = (long)sTok[arow] * HIDDEN;

  f32x4 acc[4][4];
  #pragma unroll
  for (int i = 0; i < 4; ++i)
    #pragma unroll
    for (int j = 0; j < 4; ++j) { f32x4 z = {0.f, 0.f, 0.f, 0.f}; acc[i][j] = z; }

  for (int ks = 0; ks < 16; ++ks) {
    __syncthreads();
    const unsigned short* w1s = w1base + ks * 8192;
    #pragma unroll
    for (int j = 0; j < 4; ++j)
      gload16(w1s + j * 2048 + tid * 8, &sAB[8192 + j * 2048 + tid * 8]);
    {
      const float* hp = h + htok + ks * 64 + ahalf * 32;
      float4 v0 = *(const float4*)(hp + 0),  v1 = *(const float4*)(hp + 4);
      float4 v2 = *(const float4*)(hp + 8),  v3 = *(const float4*)(hp + 12);
      float4 v4 = *(const float4*)(hp + 16), v5 = *(const float4*)(hp + 20);
      float4 v6 = *(const float4*)(hp + 24), v7 = *(const float4*)(hp + 28);
      const int sb = arow * 64 + ahalf * 32;
      *(bf16x8*)&sAB[FSWZ(arow, sb + 0)]  = pack8(v0, v1);
      *(bf16x8*)&sAB[FSWZ(arow, sb + 8)]  = pack8(v2, v3);
      *(bf16x8*)&sAB[FSWZ(arow, sb + 16)] = pack8(v4, v5);
      *(bf16x8*)&sAB[FSWZ(arow, sb + 24)] = pack8(v6, v7);
    }
    __syncthreads();
    #pragma unroll
    for (int kk = 0; kk < 2; ++kk) {
      bf16x8 af[4], bfr[4];
      #pragma unroll
      for (int mf = 0; mf < 4; ++mf) {
        const int row = wr * 64 + mf * 16 + lr;
        af[mf] = *(const bf16x8*)&sAB[FSWZ(row, row * 64 + kk * 32 + lg * 8)];
      }
      #pragma unroll
      for (int nf = 0; nf < 4; ++nf) {
        const int rn = wc * 64 + nf * 16 + lr;
        bfr[nf] = *(const bf16x8*)&sAB[8192 + FSWZ(rn, rn * 64 + kk * 32 + lg * 8)];
      }
      #pragma unroll
      for (int mf = 0; mf < 4; ++mf)
        #pragma unroll
        for (int nf = 0; nf < 4; ++nf)
          acc[mf][nf] = __builtin_amdgcn_mfma_f32_16x16x32_bf16(af[mf], bfr[nf], acc[mf][nf], 0, 0, 0);
    }
  }

  float b1v[4];
  #pragma unroll
  for (int nf = 0; nf < 4; ++nf) b1v[nf] = b1g[c * BOT + wc * 64 + nf * 16 + lr];
  #pragma unroll
  for (int mf = 0; mf < 4; ++mf)
    #pragma unroll
    for (int nf = 0; nf < 4; ++nf)
      #pragma unroll
      for (int r = 0; r < 4; ++r) {
        float x = acc[mf][nf][r] + b1v[nf];
        float g = 0.5f * x * (1.0f + erff(x * 0.70710678118654752f));
        const int m = wr * 64 + mf * 16 + lg * 4 + r;
        const int n = wc * 64 + nf * 16 + lr;
        sMid[FSWZ(m, m * 128 + n)] = f2bf(g);
      }

  for (int nc = 0; nc < 16; ++nc) {
    __syncthreads();
    #pragma unroll
    for (int j = 0; j < 4; ++j)
      gload16(w2base + nc * 8192 + j * 2048 + tid * 8, &sAB[j * 2048 + tid * 8]);
    __syncthreads();

    f32x4 a2[4][2];
    #pragma unroll
    for (int i = 0; i < 4; ++i)
      #pragma unroll
      for (int j = 0; j < 2; ++j) { f32x4 z = {0.f, 0.f, 0.f, 0.f}; a2[i][j] = z; }

    #pragma unroll
    for (int kk = 0; kk < 4; ++kk) {
      bf16x8 af[4], bfr[2];
      #pragma unroll
      for (int mf = 0; mf < 4; ++mf) {
        const int m = wr * 64 + mf * 16 + lr;
        af[mf] = *(const bf16x8*)&sMid[FSWZ(m, m * 128 + kk * 32 + lg * 8)];
      }
      #pragma unroll
      for (int nf = 0; nf < 2; ++nf) {
        const int rn = wc * 32 + nf * 16 + lr;
        bfr[nf] = *(const bf16x8*)&sAB[FSWZ(rn, rn * 128 + kk * 32 + lg * 8)];
      }
      #pragma unroll
      for (int mf = 0; mf < 4; ++mf)
        #pragma unroll
        for (int nf = 0; nf < 2; ++nf)
          a2[mf][nf] = __builtin_amdgcn_mfma_f32_16x16x32_bf16(af[mf], bfr[nf], a2[mf][nf], 0, 0, 0);
    }

    #pragma unroll
    for (int nf = 0; nf < 2; ++nf) {
      const int nn = nc * 64 + wc * 32 + nf * 16 + lr;
      const float b2v = b2g[c * HIDDEN + nn];
      #pragma unroll
      for (int mf = 0; mf < 4; ++mf)
        #pragma unroll
        for (int r = 0; r < 4; ++r) {
          const int m = wr * 64 + mf * 16 + lg * 4 + r;
          if (m < nvalid) {
            const long tk = (long)sTok[m] * HIDDEN;
            out[tk + nn] = h[tk + nn] + a2[mf][nf][r] + b2v;
          }
        }
    }
  }
}

// ---------------- launcher ----------------
extern "C" void kernel_launch(void* const* d_in, const int* in_sizes, int n_in,
                              void* d_out, int out_size, void* d_ws, size_t ws_size,
                              hipStream_t stream) {
  const float* h   = (const float*)d_in[0];
  const int*   ids = (const int*)d_in[1];
  const float* W1  = (const float*)d_in[2];
  const float* b1  = (const float*)d_in[3];
  const float* W2  = (const float*)d_in[4];
  const float* b2  = (const float*)d_in[5];
  float* out = (float*)d_out;

  char* ws = (char*)d_ws;
  int* counts  = (int*)ws;            // 16 ints
  int* cursor  = (int*)(ws + 64);     // 16 ints
  int* offsets = (int*)(ws + 128);    // 17 ints
  int* perm    = (int*)(ws + 256);    // 65536 ints, ends at 262400
  unsigned short* W1til = (unsigned short*)(ws + 262400);             // 4 MB
  unsigned short* W2til = W1til + (size_t)16 * 16 * 8192;             // 4 MB
  unsigned short* midg  = W2til + (size_t)16 * 16 * 8192;             // 16 MB
  const size_t need = 262400 + 2 * (size_t)16 * 16 * 8192 * 2 +
                      (size_t)NTOK * BOT * 2;

  k_zero<<<1, 64, 0, stream>>>(counts);
  k_hist<<<256, 256, 0, stream>>>(ids, counts);
  k_scan<<<1, 64, 0, stream>>>(counts, offsets, cursor);
  k_scatter<<<NTOK / 256, 256, 0, stream>>>(ids, cursor, perm);
  k_w1til<<<1024, 256, 0, stream>>>(W1, W1til);
  k_w2til<<<1024, 256, 0, stream>>>(W2, W2til);

  if (ws_size >= need) {
    const int nwg = NTOK / 64 + NUM_CLUSTERS;
    k_gemm1<<<nwg, 512, 0, stream>>>(h, b1, W1til, offsets, perm, midg);
    k_gemm2<<<nwg, 512, 0, stream>>>(h, b2, W2til, offsets, perm, midg, out);
  } else {
    k_fused<<<NTOK / 128 + NUM_CLUSTERS, 256, 0, stream>>>(
        h, b1, b2, W1til, W2til, offsets, perm, out);
  }
}